// Round 3
// baseline (829.371 us; speedup 1.0000x reference)
//
#include <hip/hip_runtime.h>
#include <hip/hip_bf16.h>

#define N_NODES 100000

typedef unsigned short ushort_t;
typedef __attribute__((ext_vector_type(8))) short short8;
typedef __attribute__((ext_vector_type(4))) float f32x4;

// ---------------------------------------------------------------------------
// helpers
// ---------------------------------------------------------------------------
static __device__ __forceinline__ ushort_t f2bf(float f) {
    unsigned u = __float_as_uint(f);
    unsigned r = u + 0x7FFFu + ((u >> 16) & 1u);   // round-to-nearest-even
    return (ushort_t)(r >> 16);
}
static __device__ __forceinline__ float bf2f(ushort_t h) {
    return __uint_as_float(((unsigned)h) << 16);
}

// split 8 contiguous fp32 into hi/lo bf16 fragments
static __device__ __forceinline__ void split8(const float* __restrict__ xp,
                                              short8& hi, short8& lo) {
    float4 x0 = *(const float4*)xp;
    float4 x1 = *(const float4*)(xp + 4);
    float xs[8] = {x0.x, x0.y, x0.z, x0.w, x1.x, x1.y, x1.z, x1.w};
    #pragma unroll
    for (int j = 0; j < 8; ++j) {
        ushort_t h = f2bf(xs[j]);
        hi[j] = (short)h;
        lo[j] = (short)f2bf(xs[j] - bf2f(h));
    }
}

// ---------------------------------------------------------------------------
// CSR build: histogram -> chunked scan -> fill
// ---------------------------------------------------------------------------
__global__ __launch_bounds__(256) void hist_kernel(const int* __restrict__ dst,
                                                   int* __restrict__ deg, int E) {
    int e = blockIdx.x * 256 + threadIdx.x;
    if (e < E) atomicAdd(&deg[dst[e]], 1);
}

// single block, each thread owns a contiguous chunk; one cross-thread scan
__global__ __launch_bounds__(1024) void scan_kernel(const int* __restrict__ deg,
                                                    int* __restrict__ row_ptr,
                                                    int* __restrict__ cursor,
                                                    float* __restrict__ inv_deg, int N) {
    __shared__ int wsums[16];
    int tid = threadIdx.x;
    int lane = tid & 63, wv = tid >> 6;
    const int C = (N + 1023) / 1024;
    int lo = tid * C;
    int hi = min(lo + C, N);

    int sum = 0;
    for (int i = lo; i < hi; ++i) sum += deg[i];

    // inclusive scan of per-thread sums (wave shuffle + LDS cross-wave)
    int x = sum;
    #pragma unroll
    for (int off = 1; off < 64; off <<= 1) {
        int y = __shfl_up(x, off, 64);
        if (lane >= off) x += y;
    }
    if (lane == 63) wsums[wv] = x;
    __syncthreads();
    int woff = 0;
    for (int w = 0; w < wv; ++w) woff += wsums[w];
    int run = woff + x - sum;   // exclusive prefix for this thread's chunk

    for (int i = lo; i < hi; ++i) {
        int d = deg[i];
        row_ptr[i] = run;
        cursor[i]  = run;
        inv_deg[i] = 1.0f / (float)(d > 0 ? d : 1);
        run += d;
    }
    if (lo < N && hi == N) row_ptr[N] = run;
}

__global__ __launch_bounds__(256) void fill_kernel(const int* __restrict__ src,
                                                   const int* __restrict__ dst,
                                                   int* __restrict__ cursor,
                                                   int* __restrict__ edge_src, int E) {
    int e = blockIdx.x * 256 + threadIdx.x;
    if (e < E) {
        int d = dst[e];
        int p = atomicAdd(&cursor[d], 1);
        edge_src[p] = src[e];
    }
}

// ---------------------------------------------------------------------------
// Weight pre-pack: W[K x NS] fp32 row-major -> MFMA B-fragment order, hi/lo bf16.
// Fragment (s = k-step, t = n-tile): lane l, j in 0..7 holds
//   W[k = s*32 + (l>>4)*8 + j][n = t*16 + (l&15)]
// packed at element offset ((s*NT + t)*64 + l)*8 + j.
// ---------------------------------------------------------------------------
__global__ __launch_bounds__(256) void pack_w(const float* __restrict__ W,
                                              ushort_t* __restrict__ Hi,
                                              ushort_t* __restrict__ Lo,
                                              int K, int NS) {
    int tid = blockIdx.x * 256 + threadIdx.x;
    int total = (K * NS) / 8;
    if (tid >= total) return;
    int l  = tid & 63;
    int fl = tid >> 6;
    int NT = NS / 16;
    int t = fl % NT, s = fl / NT;
    ushort_t hs[8], ls[8];
    #pragma unroll
    for (int j = 0; j < 8; ++j) {
        int k = s * 32 + (l >> 4) * 8 + j;
        int n = t * 16 + (l & 15);
        float w = W[(size_t)k * NS + n];
        ushort_t h = f2bf(w);
        hs[j] = h;
        ls[j] = f2bf(w - bf2f(h));
    }
    #pragma unroll
    for (int j = 0; j < 8; ++j) {
        Hi[(size_t)tid * 8 + j] = hs[j];
        Lo[(size_t)tid * 8 + j] = ls[j];
    }
}

// ---------------------------------------------------------------------------
// MFMA dual GEMM (split-bf16, fp32-grade):
//   S[M,NS]  = X @ Ws + bias  (fp32 out)
//   Zb[M,NS] = X @ Wn         (bf16 out)
// X fp32 row-major, split to hi/lo bf16 in-register. Weights pre-packed.
// Block: 256 thr = 4 waves; wave owns 32 rows (2 m-tiles); block = 128 rows.
// No LDS, no barriers. x ~= hi+lo; x*w ~= hi*hi + lo*hi + hi*lo.
// ---------------------------------------------------------------------------
template <int K, int NS>
__global__ __launch_bounds__(256) void mfma_gemm(const float* __restrict__ X,
                                                 const ushort_t* __restrict__ BsHi,
                                                 const ushort_t* __restrict__ BsLo,
                                                 const ushort_t* __restrict__ BnHi,
                                                 const ushort_t* __restrict__ BnLo,
                                                 const float* __restrict__ bias,
                                                 float* __restrict__ S,
                                                 ushort_t* __restrict__ Zb,
                                                 int M) {
    constexpr int KS = K / 32;      // mfma k-steps
    constexpr int NT = NS / 16;     // n-tiles
    int tid = threadIdx.x;
    int lane = tid & 63, w = tid >> 6;
    int baseM = blockIdx.x * 128 + w * 32;
    int rIn = lane & 15, q = lane >> 4;

    // ---- load + split all A fragments for this wave's 32 rows ----
    short8 Ahi[KS][2], Alo[KS][2];
    #pragma unroll
    for (int s = 0; s < KS; ++s) {
        #pragma unroll
        for (int mt = 0; mt < 2; ++mt) {
            int gm = baseM + mt * 16 + rIn;
            if (gm < M) {
                split8(&X[(size_t)gm * K + s * 32 + q * 8], Ahi[s][mt], Alo[s][mt]);
            } else {
                #pragma unroll
                for (int j = 0; j < 8; ++j) { Ahi[s][mt][j] = 0; Alo[s][mt][j] = 0; }
            }
        }
    }

    // ---- loop n-tiles; stream B frags from L2; 12 MFMA per (s,t) ----
    for (int t = 0; t < NT; ++t) {
        f32x4 aS0 = {0.f, 0.f, 0.f, 0.f}, aS1 = {0.f, 0.f, 0.f, 0.f};
        f32x4 aZ0 = {0.f, 0.f, 0.f, 0.f}, aZ1 = {0.f, 0.f, 0.f, 0.f};
        #pragma unroll
        for (int s = 0; s < KS; ++s) {
            size_t fo = ((size_t)(s * NT + t) * 64 + lane) * 8;
            short8 bsh = *(const short8*)&BsHi[fo];
            short8 bsl = *(const short8*)&BsLo[fo];
            short8 bnh = *(const short8*)&BnHi[fo];
            short8 bnl = *(const short8*)&BnLo[fo];
            aS0 = __builtin_amdgcn_mfma_f32_16x16x32_bf16(Ahi[s][0], bsh, aS0, 0, 0, 0);
            aS0 = __builtin_amdgcn_mfma_f32_16x16x32_bf16(Alo[s][0], bsh, aS0, 0, 0, 0);
            aS0 = __builtin_amdgcn_mfma_f32_16x16x32_bf16(Ahi[s][0], bsl, aS0, 0, 0, 0);
            aS1 = __builtin_amdgcn_mfma_f32_16x16x32_bf16(Ahi[s][1], bsh, aS1, 0, 0, 0);
            aS1 = __builtin_amdgcn_mfma_f32_16x16x32_bf16(Alo[s][1], bsh, aS1, 0, 0, 0);
            aS1 = __builtin_amdgcn_mfma_f32_16x16x32_bf16(Ahi[s][1], bsl, aS1, 0, 0, 0);
            aZ0 = __builtin_amdgcn_mfma_f32_16x16x32_bf16(Ahi[s][0], bnh, aZ0, 0, 0, 0);
            aZ0 = __builtin_amdgcn_mfma_f32_16x16x32_bf16(Alo[s][0], bnh, aZ0, 0, 0, 0);
            aZ0 = __builtin_amdgcn_mfma_f32_16x16x32_bf16(Ahi[s][0], bnl, aZ0, 0, 0, 0);
            aZ1 = __builtin_amdgcn_mfma_f32_16x16x32_bf16(Ahi[s][1], bnh, aZ1, 0, 0, 0);
            aZ1 = __builtin_amdgcn_mfma_f32_16x16x32_bf16(Alo[s][1], bnh, aZ1, 0, 0, 0);
            aZ1 = __builtin_amdgcn_mfma_f32_16x16x32_bf16(Ahi[s][1], bnl, aZ1, 0, 0, 0);
        }
        // epilogue: C/D layout col = lane&15, row = (lane>>4)*4 + reg
        int col = t * 16 + rIn;
        float bv = bias[col];
        #pragma unroll
        for (int mt = 0; mt < 2; ++mt) {
            f32x4 aS = mt ? aS1 : aS0;
            f32x4 aZ = mt ? aZ1 : aZ0;
            #pragma unroll
            for (int r = 0; r < 4; ++r) {
                int gm = baseM + mt * 16 + q * 4 + r;
                if (gm < M) {
                    S[(size_t)gm * NS + col]  = aS[r] + bv;
                    Zb[(size_t)gm * NS + col] = f2bf(aZ[r]);
                }
            }
        }
    }
}

// ---------------------------------------------------------------------------
// Aggregate with bf16 Z: out[n,f] = act( S[n,f] + inv_deg[n]*sum Z[src,f] )
// Each lane covers 4 features (uint2 = 4 bf16). ACT: 0 = relu, 1 = softmax(D=64)
// ---------------------------------------------------------------------------
template <int D, int ACT>
__global__ __launch_bounds__(256) void agg_kernel(const float* __restrict__ S,
                                                  const uint2* __restrict__ Zu,
                                                  const int* __restrict__ row_ptr,
                                                  const int* __restrict__ edge_src,
                                                  const float* __restrict__ inv_deg,
                                                  float* __restrict__ out, int N) {
    constexpr int G  = D / 4;          // lanes per node
    constexpr int NG = 256 / G;        // nodes per block
    int tid = threadIdx.x;
    int g = tid / G, f4 = tid % G;
    int n = blockIdx.x * NG + g;
    if (n >= N) return;
    int beg = row_ptr[n], end = row_ptr[n + 1];

    float a0[4] = {0, 0, 0, 0}, a1[4] = {0, 0, 0, 0};
    float a2[4] = {0, 0, 0, 0}, a3[4] = {0, 0, 0, 0};
#define ACC(u, a)                                                              \
    a[0] += __uint_as_float((u).x << 16);                                      \
    a[1] += __uint_as_float((u).x & 0xFFFF0000u);                              \
    a[2] += __uint_as_float((u).y << 16);                                      \
    a[3] += __uint_as_float((u).y & 0xFFFF0000u);
    int j = beg;
    for (; j + 3 < end; j += 4) {
        int s0 = edge_src[j + 0], s1 = edge_src[j + 1];
        int s2 = edge_src[j + 2], s3 = edge_src[j + 3];
        uint2 u0 = Zu[(size_t)s0 * G + f4];
        uint2 u1 = Zu[(size_t)s1 * G + f4];
        uint2 u2 = Zu[(size_t)s2 * G + f4];
        uint2 u3 = Zu[(size_t)s3 * G + f4];
        ACC(u0, a0) ACC(u1, a1) ACC(u2, a2) ACC(u3, a3)
    }
    for (; j < end; ++j) {
        uint2 u = Zu[(size_t)edge_src[j] * G + f4];
        ACC(u, a0)
    }
#undef ACC
    float id = inv_deg[n];
    float4 sv = ((const float4*)(S + (size_t)n * D))[f4];
    float v[4];
    v[0] = sv.x + id * ((a0[0] + a1[0]) + (a2[0] + a3[0]));
    v[1] = sv.y + id * ((a0[1] + a1[1]) + (a2[1] + a3[1]));
    v[2] = sv.z + id * ((a0[2] + a1[2]) + (a2[2] + a3[2]));
    v[3] = sv.w + id * ((a0[3] + a1[3]) + (a2[3] + a3[3]));

    float4 o;
    if (ACT == 0) {
        o.x = fmaxf(v[0], 0.f); o.y = fmaxf(v[1], 0.f);
        o.z = fmaxf(v[2], 0.f); o.w = fmaxf(v[3], 0.f);
    } else {
        // softmax across G=16 lanes x 4 vals
        float m = fmaxf(fmaxf(v[0], v[1]), fmaxf(v[2], v[3]));
        #pragma unroll
        for (int off = 8; off > 0; off >>= 1) m = fmaxf(m, __shfl_xor(m, off, 16));
        float e0 = __expf(v[0] - m), e1 = __expf(v[1] - m);
        float e2 = __expf(v[2] - m), e3 = __expf(v[3] - m);
        float s = (e0 + e1) + (e2 + e3);
        #pragma unroll
        for (int off = 8; off > 0; off >>= 1) s += __shfl_xor(s, off, 16);
        float inv = 1.0f / s;
        o.x = e0 * inv; o.y = e1 * inv; o.z = e2 * inv; o.w = e3 * inv;
    }
    ((float4*)(out + (size_t)n * D))[f4] = o;
}

// ---------------------------------------------------------------------------
extern "C" void kernel_launch(void* const* d_in, const int* in_sizes, int n_in,
                              void* d_out, int out_size, void* d_ws, size_t ws_size,
                              hipStream_t stream) {
    const float* in_feat = (const float*)d_in[0];
    const int*   src     = (const int*)d_in[1];
    const int*   dst     = (const int*)d_in[2];
    const float* w1s = (const float*)d_in[3];
    const float* w1n = (const float*)d_in[4];
    const float* b1  = (const float*)d_in[5];
    const float* w2s = (const float*)d_in[6];
    const float* w2n = (const float*)d_in[7];
    const float* b2  = (const float*)d_in[8];
    const float* w3s = (const float*)d_in[9];
    const float* w3n = (const float*)d_in[10];
    const float* b3  = (const float*)d_in[11];

    const int N = N_NODES;
    const int E = in_sizes[1];

    char* p = (char*)d_ws;
    auto carve = [&](size_t bytes) -> char* {
        char* q = p;
        p += (bytes + 511) & ~(size_t)511;
        return q;
    };
    float*    S        = (float*)   carve((size_t)N * 128 * sizeof(float));
    ushort_t* Zb       = (ushort_t*)carve((size_t)N * 128 * sizeof(ushort_t));
    float*    H        = (float*)   carve((size_t)N * 128 * sizeof(float));
    int*      edge_src = (int*)     carve((size_t)E * sizeof(int));
    int*      row_ptr  = (int*)     carve((size_t)(N + 1) * sizeof(int));
    int*      cursor   = (int*)     carve((size_t)N * sizeof(int));
    int*      deg      = (int*)     carve((size_t)N * sizeof(int));
    float*    invd     = (float*)   carve((size_t)N * sizeof(float));
    // packed weights (hi/lo per matrix)
    ushort_t* P1sH = (ushort_t*)carve(128 * 128 * 2); ushort_t* P1sL = (ushort_t*)carve(128 * 128 * 2);
    ushort_t* P1nH = (ushort_t*)carve(128 * 128 * 2); ushort_t* P1nL = (ushort_t*)carve(128 * 128 * 2);
    ushort_t* P2sH = (ushort_t*)carve(128 * 64 * 2);  ushort_t* P2sL = (ushort_t*)carve(128 * 64 * 2);
    ushort_t* P2nH = (ushort_t*)carve(128 * 64 * 2);  ushort_t* P2nL = (ushort_t*)carve(128 * 64 * 2);
    ushort_t* P3sH = (ushort_t*)carve(64 * 64 * 2);   ushort_t* P3sL = (ushort_t*)carve(64 * 64 * 2);
    ushort_t* P3nH = (ushort_t*)carve(64 * 64 * 2);   ushort_t* P3nL = (ushort_t*)carve(64 * 64 * 2);

    // ---- weight packing (tiny) ----
    pack_w<<<(128 * 128 / 8 + 255) / 256, 256, 0, stream>>>(w1s, P1sH, P1sL, 128, 128);
    pack_w<<<(128 * 128 / 8 + 255) / 256, 256, 0, stream>>>(w1n, P1nH, P1nL, 128, 128);
    pack_w<<<(128 * 64 / 8 + 255) / 256, 256, 0, stream>>>(w2s, P2sH, P2sL, 128, 64);
    pack_w<<<(128 * 64 / 8 + 255) / 256, 256, 0, stream>>>(w2n, P2nH, P2nL, 128, 64);
    pack_w<<<(64 * 64 / 8 + 255) / 256, 256, 0, stream>>>(w3s, P3sH, P3sL, 64, 64);
    pack_w<<<(64 * 64 / 8 + 255) / 256, 256, 0, stream>>>(w3n, P3nH, P3nL, 64, 64);

    // ---- CSR build ----
    hipMemsetAsync(deg, 0, (size_t)N * sizeof(int), stream);
    hist_kernel<<<(E + 255) / 256, 256, 0, stream>>>(dst, deg, E);
    scan_kernel<<<1, 1024, 0, stream>>>(deg, row_ptr, cursor, invd, N);
    fill_kernel<<<(E + 255) / 256, 256, 0, stream>>>(src, dst, cursor, edge_src, E);

    const int GB = (N + 127) / 128;   // 782 row blocks

    // ---- Layer 1: 128 -> 128, relu ----
    mfma_gemm<128, 128><<<GB, 256, 0, stream>>>(in_feat, P1sH, P1sL, P1nH, P1nL, b1, S, Zb, N);
    agg_kernel<128, 0><<<(N + 7) / 8, 256, 0, stream>>>(S, (const uint2*)Zb,
                                                        row_ptr, edge_src, invd, H, N);

    // ---- Layer 2: 128 -> 64, relu ----
    mfma_gemm<128, 64><<<GB, 256, 0, stream>>>(H, P2sH, P2sL, P2nH, P2nL, b2, S, Zb, N);
    agg_kernel<64, 0><<<(N + 15) / 16, 256, 0, stream>>>(S, (const uint2*)Zb,
                                                         row_ptr, edge_src, invd, H, N);

    // ---- Layer 3: 64 -> 64, softmax ----
    mfma_gemm<64, 64><<<GB, 256, 0, stream>>>(H, P3sH, P3sL, P3nH, P3nL, b3, S, Zb, N);
    agg_kernel<64, 1><<<(N + 15) / 16, 256, 0, stream>>>(S, (const uint2*)Zb,
                                                         row_ptr, edge_src, invd,
                                                         (float*)d_out, N);
}

// Round 4
// 564.781 us; speedup vs baseline: 1.4685x; 1.4685x over previous
//
#include <hip/hip_runtime.h>
#include <hip/hip_bf16.h>

#define N_NODES 100000

typedef unsigned short ushort_t;
typedef __attribute__((ext_vector_type(8))) short short8;
typedef __attribute__((ext_vector_type(4))) float f32x4;

// ---------------------------------------------------------------------------
// helpers
// ---------------------------------------------------------------------------
static __device__ __forceinline__ ushort_t f2bf(float f) {
    unsigned u = __float_as_uint(f);
    unsigned r = u + 0x7FFFu + ((u >> 16) & 1u);   // round-to-nearest-even
    return (ushort_t)(r >> 16);
}
static __device__ __forceinline__ float bf2f(ushort_t h) {
    return __uint_as_float(((unsigned)h) << 16);
}

// split 8 contiguous fp32 into hi/lo bf16 fragments
static __device__ __forceinline__ void split8(const float* __restrict__ xp,
                                              short8& hi, short8& lo) {
    float4 x0 = *(const float4*)xp;
    float4 x1 = *(const float4*)(xp + 4);
    float xs[8] = {x0.x, x0.y, x0.z, x0.w, x1.x, x1.y, x1.z, x1.w};
    #pragma unroll
    for (int j = 0; j < 8; ++j) {
        ushort_t h = f2bf(xs[j]);
        hi[j] = (short)h;
        lo[j] = (short)f2bf(xs[j] - bf2f(h));
    }
}

// ---------------------------------------------------------------------------
// CSR build: histogram -> 3-phase multi-block scan -> fill
// ---------------------------------------------------------------------------
__global__ __launch_bounds__(256) void hist_kernel(const int* __restrict__ dst,
                                                   int* __restrict__ deg, int E) {
    int e = blockIdx.x * 256 + threadIdx.x;
    if (e < E) atomicAdd(&deg[dst[e]], 1);
}

// phase 1: per-block (1024-elem segment) total
__global__ __launch_bounds__(256) void scan_partial_sums(const int* __restrict__ deg,
                                                         int* __restrict__ partials, int N) {
    __shared__ int wsums[4];
    int tid = threadIdx.x, lane = tid & 63, wv = tid >> 6;
    int i0 = blockIdx.x * 1024 + tid * 4;
    int s = 0;
    #pragma unroll
    for (int j = 0; j < 4; ++j) {
        int i = i0 + j;
        if (i < N) s += deg[i];
    }
    #pragma unroll
    for (int off = 32; off > 0; off >>= 1) s += __shfl_xor(s, off, 64);
    if (lane == 0) wsums[wv] = s;
    __syncthreads();
    if (tid == 0)
        partials[blockIdx.x] = wsums[0] + wsums[1] + wsums[2] + wsums[3];
}

// phase 2: single block scans NB (<=256) partials -> exclusive, writes row_ptr[N]
__global__ __launch_bounds__(256) void scan_partials(int* __restrict__ partials, int NB,
                                                     int* __restrict__ row_ptr, int N) {
    __shared__ int wsums[4];
    int tid = threadIdx.x, lane = tid & 63, wv = tid >> 6;
    int v = (tid < NB) ? partials[tid] : 0;
    int x = v;
    #pragma unroll
    for (int off = 1; off < 64; off <<= 1) {
        int y = __shfl_up(x, off, 64);
        if (lane >= off) x += y;
    }
    if (lane == 63) wsums[wv] = x;
    __syncthreads();
    int woff = 0;
    for (int w = 0; w < wv; ++w) woff += wsums[w];
    int incl = x + woff;
    if (tid < NB) partials[tid] = incl - v;          // exclusive
    if (tid == NB - 1) row_ptr[N] = incl;            // grand total
}

// phase 3: re-read segment, local scan + block offset, emit row_ptr/cursor/invd
__global__ __launch_bounds__(256) void scan_emit(const int* __restrict__ deg,
                                                 const int* __restrict__ partials,
                                                 int* __restrict__ row_ptr,
                                                 int* __restrict__ cursor,
                                                 float* __restrict__ inv_deg, int N) {
    __shared__ int wsums[4];
    int tid = threadIdx.x, lane = tid & 63, wv = tid >> 6;
    int i0 = blockIdx.x * 1024 + tid * 4;
    int d[4];
    #pragma unroll
    for (int j = 0; j < 4; ++j) {
        int i = i0 + j;
        d[j] = (i < N) ? deg[i] : 0;
    }
    int s = d[0] + d[1] + d[2] + d[3];
    int x = s;
    #pragma unroll
    for (int off = 1; off < 64; off <<= 1) {
        int y = __shfl_up(x, off, 64);
        if (lane >= off) x += y;
    }
    if (lane == 63) wsums[wv] = x;
    __syncthreads();
    int woff = 0;
    for (int w = 0; w < wv; ++w) woff += wsums[w];
    int run = partials[blockIdx.x] + woff + x - s;   // exclusive prefix of elem i0
    #pragma unroll
    for (int j = 0; j < 4; ++j) {
        int i = i0 + j;
        if (i < N) {
            row_ptr[i] = run;
            cursor[i]  = run;
            inv_deg[i] = 1.0f / (float)(d[j] > 0 ? d[j] : 1);
            run += d[j];
        }
    }
}

__global__ __launch_bounds__(256) void fill_kernel(const int* __restrict__ src,
                                                   const int* __restrict__ dst,
                                                   int* __restrict__ cursor,
                                                   int* __restrict__ edge_src, int E) {
    int e = blockIdx.x * 256 + threadIdx.x;
    if (e < E) {
        int d = dst[e];
        int p = atomicAdd(&cursor[d], 1);
        edge_src[p] = src[e];
    }
}

// ---------------------------------------------------------------------------
// Weight pre-pack: W[K x NS] fp32 row-major -> MFMA B-fragment order, hi/lo bf16.
// Fragment (s = k-step, t = n-tile): lane l, j in 0..7 holds
//   W[k = s*32 + (l>>4)*8 + j][n = t*16 + (l&15)]
// packed at element offset ((s*NT + t)*64 + l)*8 + j.
// ---------------------------------------------------------------------------
__global__ __launch_bounds__(256) void pack_w(const float* __restrict__ W,
                                              ushort_t* __restrict__ Hi,
                                              ushort_t* __restrict__ Lo,
                                              int K, int NS) {
    int tid = blockIdx.x * 256 + threadIdx.x;
    int total = (K * NS) / 8;
    if (tid >= total) return;
    int l  = tid & 63;
    int fl = tid >> 6;
    int NT = NS / 16;
    int t = fl % NT, s = fl / NT;
    ushort_t hs[8], ls[8];
    #pragma unroll
    for (int j = 0; j < 8; ++j) {
        int k = s * 32 + (l >> 4) * 8 + j;
        int n = t * 16 + (l & 15);
        float w = W[(size_t)k * NS + n];
        ushort_t h = f2bf(w);
        hs[j] = h;
        ls[j] = f2bf(w - bf2f(h));
    }
    #pragma unroll
    for (int j = 0; j < 8; ++j) {
        Hi[(size_t)tid * 8 + j] = hs[j];
        Lo[(size_t)tid * 8 + j] = ls[j];
    }
}

// ---------------------------------------------------------------------------
// MFMA dual GEMM (split-bf16, fp32-grade):
//   S[M,NS]  = X @ Ws + bias  (fp32 out)
//   Zb[M,NS] = X @ Wn         (bf16 out)
// X fp32 row-major, split to hi/lo bf16 in-register. Weights pre-packed.
// Block: 256 thr = 4 waves; wave owns 32 rows (2 m-tiles); block = 128 rows.
// No LDS, no barriers. x ~= hi+lo; x*w ~= hi*hi + lo*hi + hi*lo.
// ---------------------------------------------------------------------------
template <int K, int NS>
__global__ __launch_bounds__(256) void mfma_gemm(const float* __restrict__ X,
                                                 const ushort_t* __restrict__ BsHi,
                                                 const ushort_t* __restrict__ BsLo,
                                                 const ushort_t* __restrict__ BnHi,
                                                 const ushort_t* __restrict__ BnLo,
                                                 const float* __restrict__ bias,
                                                 float* __restrict__ S,
                                                 ushort_t* __restrict__ Zb,
                                                 int M) {
    constexpr int KS = K / 32;      // mfma k-steps
    constexpr int NT = NS / 16;     // n-tiles
    int tid = threadIdx.x;
    int lane = tid & 63, w = tid >> 6;
    int baseM = blockIdx.x * 128 + w * 32;
    int rIn = lane & 15, q = lane >> 4;

    // ---- load + split all A fragments for this wave's 32 rows ----
    short8 Ahi[KS][2], Alo[KS][2];
    #pragma unroll
    for (int s = 0; s < KS; ++s) {
        #pragma unroll
        for (int mt = 0; mt < 2; ++mt) {
            int gm = baseM + mt * 16 + rIn;
            if (gm < M) {
                split8(&X[(size_t)gm * K + s * 32 + q * 8], Ahi[s][mt], Alo[s][mt]);
            } else {
                #pragma unroll
                for (int j = 0; j < 8; ++j) { Ahi[s][mt][j] = 0; Alo[s][mt][j] = 0; }
            }
        }
    }

    // ---- loop n-tiles; stream B frags from L2; 12 MFMA per (s,t) ----
    for (int t = 0; t < NT; ++t) {
        f32x4 aS0 = {0.f, 0.f, 0.f, 0.f}, aS1 = {0.f, 0.f, 0.f, 0.f};
        f32x4 aZ0 = {0.f, 0.f, 0.f, 0.f}, aZ1 = {0.f, 0.f, 0.f, 0.f};
        #pragma unroll
        for (int s = 0; s < KS; ++s) {
            size_t fo = ((size_t)(s * NT + t) * 64 + lane) * 8;
            short8 bsh = *(const short8*)&BsHi[fo];
            short8 bsl = *(const short8*)&BsLo[fo];
            short8 bnh = *(const short8*)&BnHi[fo];
            short8 bnl = *(const short8*)&BnLo[fo];
            aS0 = __builtin_amdgcn_mfma_f32_16x16x32_bf16(Ahi[s][0], bsh, aS0, 0, 0, 0);
            aS0 = __builtin_amdgcn_mfma_f32_16x16x32_bf16(Alo[s][0], bsh, aS0, 0, 0, 0);
            aS0 = __builtin_amdgcn_mfma_f32_16x16x32_bf16(Ahi[s][0], bsl, aS0, 0, 0, 0);
            aS1 = __builtin_amdgcn_mfma_f32_16x16x32_bf16(Ahi[s][1], bsh, aS1, 0, 0, 0);
            aS1 = __builtin_amdgcn_mfma_f32_16x16x32_bf16(Alo[s][1], bsh, aS1, 0, 0, 0);
            aS1 = __builtin_amdgcn_mfma_f32_16x16x32_bf16(Ahi[s][1], bsl, aS1, 0, 0, 0);
            aZ0 = __builtin_amdgcn_mfma_f32_16x16x32_bf16(Ahi[s][0], bnh, aZ0, 0, 0, 0);
            aZ0 = __builtin_amdgcn_mfma_f32_16x16x32_bf16(Alo[s][0], bnh, aZ0, 0, 0, 0);
            aZ0 = __builtin_amdgcn_mfma_f32_16x16x32_bf16(Ahi[s][0], bnl, aZ0, 0, 0, 0);
            aZ1 = __builtin_amdgcn_mfma_f32_16x16x32_bf16(Ahi[s][1], bnh, aZ1, 0, 0, 0);
            aZ1 = __builtin_amdgcn_mfma_f32_16x16x32_bf16(Alo[s][1], bnh, aZ1, 0, 0, 0);
            aZ1 = __builtin_amdgcn_mfma_f32_16x16x32_bf16(Ahi[s][1], bnl, aZ1, 0, 0, 0);
        }
        // epilogue: C/D layout col = lane&15, row = (lane>>4)*4 + reg
        int col = t * 16 + rIn;
        float bv = bias[col];
        #pragma unroll
        for (int mt = 0; mt < 2; ++mt) {
            f32x4 aS = mt ? aS1 : aS0;
            f32x4 aZ = mt ? aZ1 : aZ0;
            #pragma unroll
            for (int r = 0; r < 4; ++r) {
                int gm = baseM + mt * 16 + q * 4 + r;
                if (gm < M) {
                    S[(size_t)gm * NS + col]  = aS[r] + bv;
                    Zb[(size_t)gm * NS + col] = f2bf(aZ[r]);
                }
            }
        }
    }
}

// ---------------------------------------------------------------------------
// Aggregate with bf16 Z: out[n,f] = act( S[n,f] + inv_deg[n]*sum Z[src,f] )
// Each lane covers 4 features (uint2 = 4 bf16). ACT: 0 = relu, 1 = softmax(D=64)
// ---------------------------------------------------------------------------
template <int D, int ACT>
__global__ __launch_bounds__(256) void agg_kernel(const float* __restrict__ S,
                                                  const uint2* __restrict__ Zu,
                                                  const int* __restrict__ row_ptr,
                                                  const int* __restrict__ edge_src,
                                                  const float* __restrict__ inv_deg,
                                                  float* __restrict__ out, int N) {
    constexpr int G  = D / 4;          // lanes per node
    constexpr int NG = 256 / G;        // nodes per block
    int tid = threadIdx.x;
    int g = tid / G, f4 = tid % G;
    int n = blockIdx.x * NG + g;
    if (n >= N) return;
    int beg = row_ptr[n], end = row_ptr[n + 1];

    float a0[4] = {0, 0, 0, 0}, a1[4] = {0, 0, 0, 0};
    float a2[4] = {0, 0, 0, 0}, a3[4] = {0, 0, 0, 0};
#define ACC(u, a)                                                              \
    a[0] += __uint_as_float((u).x << 16);                                      \
    a[1] += __uint_as_float((u).x & 0xFFFF0000u);                              \
    a[2] += __uint_as_float((u).y << 16);                                      \
    a[3] += __uint_as_float((u).y & 0xFFFF0000u);
    int j = beg;
    for (; j + 3 < end; j += 4) {
        int s0 = edge_src[j + 0], s1 = edge_src[j + 1];
        int s2 = edge_src[j + 2], s3 = edge_src[j + 3];
        uint2 u0 = Zu[(size_t)s0 * G + f4];
        uint2 u1 = Zu[(size_t)s1 * G + f4];
        uint2 u2 = Zu[(size_t)s2 * G + f4];
        uint2 u3 = Zu[(size_t)s3 * G + f4];
        ACC(u0, a0) ACC(u1, a1) ACC(u2, a2) ACC(u3, a3)
    }
    for (; j < end; ++j) {
        uint2 u = Zu[(size_t)edge_src[j] * G + f4];
        ACC(u, a0)
    }
#undef ACC
    float id = inv_deg[n];
    float4 sv = ((const float4*)(S + (size_t)n * D))[f4];
    float v[4];
    v[0] = sv.x + id * ((a0[0] + a1[0]) + (a2[0] + a3[0]));
    v[1] = sv.y + id * ((a0[1] + a1[1]) + (a2[1] + a3[1]));
    v[2] = sv.z + id * ((a0[2] + a1[2]) + (a2[2] + a3[2]));
    v[3] = sv.w + id * ((a0[3] + a1[3]) + (a2[3] + a3[3]));

    float4 o;
    if (ACT == 0) {
        o.x = fmaxf(v[0], 0.f); o.y = fmaxf(v[1], 0.f);
        o.z = fmaxf(v[2], 0.f); o.w = fmaxf(v[3], 0.f);
    } else {
        // softmax across G=16 lanes x 4 vals
        float m = fmaxf(fmaxf(v[0], v[1]), fmaxf(v[2], v[3]));
        #pragma unroll
        for (int off = 8; off > 0; off >>= 1) m = fmaxf(m, __shfl_xor(m, off, 16));
        float e0 = __expf(v[0] - m), e1 = __expf(v[1] - m);
        float e2 = __expf(v[2] - m), e3 = __expf(v[3] - m);
        float s = (e0 + e1) + (e2 + e3);
        #pragma unroll
        for (int off = 8; off > 0; off >>= 1) s += __shfl_xor(s, off, 16);
        float inv = 1.0f / s;
        o.x = e0 * inv; o.y = e1 * inv; o.z = e2 * inv; o.w = e3 * inv;
    }
    ((float4*)(out + (size_t)n * D))[f4] = o;
}

// ---------------------------------------------------------------------------
extern "C" void kernel_launch(void* const* d_in, const int* in_sizes, int n_in,
                              void* d_out, int out_size, void* d_ws, size_t ws_size,
                              hipStream_t stream) {
    const float* in_feat = (const float*)d_in[0];
    const int*   src     = (const int*)d_in[1];
    const int*   dst     = (const int*)d_in[2];
    const float* w1s = (const float*)d_in[3];
    const float* w1n = (const float*)d_in[4];
    const float* b1  = (const float*)d_in[5];
    const float* w2s = (const float*)d_in[6];
    const float* w2n = (const float*)d_in[7];
    const float* b2  = (const float*)d_in[8];
    const float* w3s = (const float*)d_in[9];
    const float* w3n = (const float*)d_in[10];
    const float* b3  = (const float*)d_in[11];

    const int N = N_NODES;
    const int E = in_sizes[1];

    char* p = (char*)d_ws;
    auto carve = [&](size_t bytes) -> char* {
        char* q = p;
        p += (bytes + 511) & ~(size_t)511;
        return q;
    };
    float*    S        = (float*)   carve((size_t)N * 128 * sizeof(float));
    ushort_t* Zb       = (ushort_t*)carve((size_t)N * 128 * sizeof(ushort_t));
    float*    H        = (float*)   carve((size_t)N * 128 * sizeof(float));
    int*      edge_src = (int*)     carve((size_t)E * sizeof(int));
    int*      row_ptr  = (int*)     carve((size_t)(N + 1) * sizeof(int));
    int*      cursor   = (int*)     carve((size_t)N * sizeof(int));
    int*      deg      = (int*)     carve((size_t)N * sizeof(int));
    float*    invd     = (float*)   carve((size_t)N * sizeof(float));
    int*      partials = (int*)     carve(256 * sizeof(int));
    // packed weights (hi/lo per matrix)
    ushort_t* P1sH = (ushort_t*)carve(128 * 128 * 2); ushort_t* P1sL = (ushort_t*)carve(128 * 128 * 2);
    ushort_t* P1nH = (ushort_t*)carve(128 * 128 * 2); ushort_t* P1nL = (ushort_t*)carve(128 * 128 * 2);
    ushort_t* P2sH = (ushort_t*)carve(128 * 64 * 2);  ushort_t* P2sL = (ushort_t*)carve(128 * 64 * 2);
    ushort_t* P2nH = (ushort_t*)carve(128 * 64 * 2);  ushort_t* P2nL = (ushort_t*)carve(128 * 64 * 2);
    ushort_t* P3sH = (ushort_t*)carve(64 * 64 * 2);   ushort_t* P3sL = (ushort_t*)carve(64 * 64 * 2);
    ushort_t* P3nH = (ushort_t*)carve(64 * 64 * 2);   ushort_t* P3nL = (ushort_t*)carve(64 * 64 * 2);

    // ---- weight packing (tiny) ----
    pack_w<<<(128 * 128 / 8 + 255) / 256, 256, 0, stream>>>(w1s, P1sH, P1sL, 128, 128);
    pack_w<<<(128 * 128 / 8 + 255) / 256, 256, 0, stream>>>(w1n, P1nH, P1nL, 128, 128);
    pack_w<<<(128 * 64 / 8 + 255) / 256, 256, 0, stream>>>(w2s, P2sH, P2sL, 128, 64);
    pack_w<<<(128 * 64 / 8 + 255) / 256, 256, 0, stream>>>(w2n, P2nH, P2nL, 128, 64);
    pack_w<<<(64 * 64 / 8 + 255) / 256, 256, 0, stream>>>(w3s, P3sH, P3sL, 64, 64);
    pack_w<<<(64 * 64 / 8 + 255) / 256, 256, 0, stream>>>(w3n, P3nH, P3nL, 64, 64);

    // ---- CSR build ----
    hipMemsetAsync(deg, 0, (size_t)N * sizeof(int), stream);
    hist_kernel<<<(E + 255) / 256, 256, 0, stream>>>(dst, deg, E);
    const int NB = (N + 1023) / 1024;   // 98 segments
    scan_partial_sums<<<NB, 256, 0, stream>>>(deg, partials, N);
    scan_partials<<<1, 256, 0, stream>>>(partials, NB, row_ptr, N);
    scan_emit<<<NB, 256, 0, stream>>>(deg, partials, row_ptr, cursor, invd, N);
    fill_kernel<<<(E + 255) / 256, 256, 0, stream>>>(src, dst, cursor, edge_src, E);

    const int GB = (N + 127) / 128;   // 782 row blocks

    // ---- Layer 1: 128 -> 128, relu ----
    mfma_gemm<128, 128><<<GB, 256, 0, stream>>>(in_feat, P1sH, P1sL, P1nH, P1nL, b1, S, Zb, N);
    agg_kernel<128, 0><<<(N + 7) / 8, 256, 0, stream>>>(S, (const uint2*)Zb,
                                                        row_ptr, edge_src, invd, H, N);

    // ---- Layer 2: 128 -> 64, relu ----
    mfma_gemm<128, 64><<<GB, 256, 0, stream>>>(H, P2sH, P2sL, P2nH, P2nL, b2, S, Zb, N);
    agg_kernel<64, 0><<<(N + 15) / 16, 256, 0, stream>>>(S, (const uint2*)Zb,
                                                         row_ptr, edge_src, invd, H, N);

    // ---- Layer 3: 64 -> 64, softmax ----
    mfma_gemm<64, 64><<<GB, 256, 0, stream>>>(H, P3sH, P3sL, P3nH, P3nL, b3, S, Zb, N);
    agg_kernel<64, 1><<<(N + 15) / 16, 256, 0, stream>>>(S, (const uint2*)Zb,
                                                         row_ptr, edge_src, invd,
                                                         (float*)d_out, N);
}

// Round 5
// 520.314 us; speedup vs baseline: 1.5940x; 1.0855x over previous
//
#include <hip/hip_runtime.h>
#include <hip/hip_bf16.h>

#define N_NODES 100000

typedef unsigned short ushort_t;
typedef __attribute__((ext_vector_type(8))) short short8;
typedef __attribute__((ext_vector_type(4))) float f32x4;

// ---------------------------------------------------------------------------
// helpers
// ---------------------------------------------------------------------------
static __device__ __forceinline__ ushort_t f2bf(float f) {
    unsigned u = __float_as_uint(f);
    unsigned r = u + 0x7FFFu + ((u >> 16) & 1u);   // round-to-nearest-even
    return (ushort_t)(r >> 16);
}
static __device__ __forceinline__ float bf2f(ushort_t h) {
    return __uint_as_float(((unsigned)h) << 16);
}

// split 8 contiguous fp32 into hi/lo bf16 fragments
static __device__ __forceinline__ void split8(const float* __restrict__ xp,
                                              short8& hi, short8& lo) {
    float4 x0 = *(const float4*)xp;
    float4 x1 = *(const float4*)(xp + 4);
    float xs[8] = {x0.x, x0.y, x0.z, x0.w, x1.x, x1.y, x1.z, x1.w};
    #pragma unroll
    for (int j = 0; j < 8; ++j) {
        ushort_t h = f2bf(xs[j]);
        hi[j] = (short)h;
        lo[j] = (short)f2bf(xs[j] - bf2f(h));
    }
}

// ---------------------------------------------------------------------------
// CSR build: histogram -> 3-phase multi-block scan -> XCD-partitioned fill
// ---------------------------------------------------------------------------
__global__ __launch_bounds__(256) void hist_kernel(const int* __restrict__ dst,
                                                   int* __restrict__ deg, int E) {
    int e = blockIdx.x * 256 + threadIdx.x;
    if (e < E) atomicAdd(&deg[dst[e]], 1);
}

// phase 1: per-block (1024-elem segment) total
__global__ __launch_bounds__(256) void scan_partial_sums(const int* __restrict__ deg,
                                                         int* __restrict__ partials, int N) {
    __shared__ int wsums[4];
    int tid = threadIdx.x, lane = tid & 63, wv = tid >> 6;
    int i0 = blockIdx.x * 1024 + tid * 4;
    int s = 0;
    #pragma unroll
    for (int j = 0; j < 4; ++j) {
        int i = i0 + j;
        if (i < N) s += deg[i];
    }
    #pragma unroll
    for (int off = 32; off > 0; off >>= 1) s += __shfl_xor(s, off, 64);
    if (lane == 0) wsums[wv] = s;
    __syncthreads();
    if (tid == 0)
        partials[blockIdx.x] = wsums[0] + wsums[1] + wsums[2] + wsums[3];
}

// phase 2: single block scans NB (<=256) partials -> exclusive, writes row_ptr[N]
__global__ __launch_bounds__(256) void scan_partials(int* __restrict__ partials, int NB,
                                                     int* __restrict__ row_ptr, int N) {
    __shared__ int wsums[4];
    int tid = threadIdx.x, lane = tid & 63, wv = tid >> 6;
    int v = (tid < NB) ? partials[tid] : 0;
    int x = v;
    #pragma unroll
    for (int off = 1; off < 64; off <<= 1) {
        int y = __shfl_up(x, off, 64);
        if (lane >= off) x += y;
    }
    if (lane == 63) wsums[wv] = x;
    __syncthreads();
    int woff = 0;
    for (int w = 0; w < wv; ++w) woff += wsums[w];
    int incl = x + woff;
    if (tid < NB) partials[tid] = incl - v;          // exclusive
    if (tid == NB - 1) row_ptr[N] = incl;            // grand total
}

// phase 3: re-read segment, local scan + block offset, emit row_ptr/cursor/invd
__global__ __launch_bounds__(256) void scan_emit(const int* __restrict__ deg,
                                                 const int* __restrict__ partials,
                                                 int* __restrict__ row_ptr,
                                                 int* __restrict__ cursor,
                                                 float* __restrict__ inv_deg, int N) {
    __shared__ int wsums[4];
    int tid = threadIdx.x, lane = tid & 63, wv = tid >> 6;
    int i0 = blockIdx.x * 1024 + tid * 4;
    int d[4];
    #pragma unroll
    for (int j = 0; j < 4; ++j) {
        int i = i0 + j;
        d[j] = (i < N) ? deg[i] : 0;
    }
    int s = d[0] + d[1] + d[2] + d[3];
    int x = s;
    #pragma unroll
    for (int off = 1; off < 64; off <<= 1) {
        int y = __shfl_up(x, off, 64);
        if (lane >= off) x += y;
    }
    if (lane == 63) wsums[wv] = x;
    __syncthreads();
    int woff = 0;
    for (int w = 0; w < wv; ++w) woff += wsums[w];
    int run = partials[blockIdx.x] + woff + x - s;   // exclusive prefix of elem i0
    #pragma unroll
    for (int j = 0; j < 4; ++j) {
        int i = i0 + j;
        if (i < N) {
            row_ptr[i] = run;
            cursor[i]  = run;
            inv_deg[i] = 1.0f / (float)(d[j] > 0 ? d[j] : 1);
            run += d[j];
        }
    }
}

// XCD-partitioned fill: group g = blockIdx&7 (maps ~to XCD g) handles dst range
// [lo,hi). Its writes land in a contiguous ~E/8*4B region that stays resident in
// that XCD's L2, so lines fill up before writeback (kills 64B/edge partial-line
// HBM write amplification). dst stream re-read 8x -> served by L3.
#define FILL_GROUPS 8
#define FILL_BPG    128
__global__ __launch_bounds__(256) void fill_part(const int* __restrict__ src,
                                                 const int* __restrict__ dst,
                                                 int* __restrict__ cursor,
                                                 int* __restrict__ edge_src,
                                                 int E, int N) {
    int g    = blockIdx.x & (FILL_GROUPS - 1);
    int bInG = blockIdx.x >> 3;
    int lo = (int)((long long)N * g / FILL_GROUPS);
    int hi = (int)((long long)N * (g + 1) / FILL_GROUPS);
    int stride = FILL_BPG * 256;
    for (int e = bInG * 256 + threadIdx.x; e < E; e += stride) {
        int d = dst[e];
        if (d >= lo && d < hi) {
            int p = atomicAdd(&cursor[d], 1);
            edge_src[p] = src[e];
        }
    }
}

// ---------------------------------------------------------------------------
// Weight pre-pack (all 6 matrices in ONE launch):
// W[K x NS] fp32 row-major -> MFMA B-fragment order, hi/lo bf16.
// Fragment (s = k-step, t = n-tile): lane l, j in 0..7 holds
//   W[k = s*32 + (l>>4)*8 + j][n = t*16 + (l&15)]
// packed at element offset ((s*NT + t)*64 + l)*8 + j.
// Blocks: job0/1 = 8 each, job2/3 = 4 each, job4/5 = 2 each (28 total).
// ---------------------------------------------------------------------------
__global__ __launch_bounds__(256) void pack_all(
        const float* __restrict__ W0, const float* __restrict__ W1,
        const float* __restrict__ W2, const float* __restrict__ W3,
        const float* __restrict__ W4, const float* __restrict__ W5,
        ushort_t* H0, ushort_t* L0, ushort_t* H1, ushort_t* L1,
        ushort_t* H2, ushort_t* L2, ushort_t* H3, ushort_t* L3,
        ushort_t* H4, ushort_t* L4, ushort_t* H5, ushort_t* L5) {
    int b = blockIdx.x;
    const float* W; ushort_t* Hi; ushort_t* Lo; int K, NS, base;
    if (b < 8)       { W = W0; Hi = H0; Lo = L0; K = 128; NS = 128; base = 0;  }
    else if (b < 16) { W = W1; Hi = H1; Lo = L1; K = 128; NS = 128; base = 8;  }
    else if (b < 20) { W = W2; Hi = H2; Lo = L2; K = 128; NS = 64;  base = 16; }
    else if (b < 24) { W = W3; Hi = H3; Lo = L3; K = 128; NS = 64;  base = 20; }
    else if (b < 26) { W = W4; Hi = H4; Lo = L4; K = 64;  NS = 64;  base = 24; }
    else             { W = W5; Hi = H5; Lo = L5; K = 64;  NS = 64;  base = 26; }
    int tid = (b - base) * 256 + threadIdx.x;
    if (tid >= (K * NS) / 8) return;
    int l  = tid & 63;
    int fl = tid >> 6;
    int NT = NS / 16;
    int t = fl % NT, s = fl / NT;
    ushort_t hs[8], ls[8];
    #pragma unroll
    for (int j = 0; j < 8; ++j) {
        int k = s * 32 + (l >> 4) * 8 + j;
        int n = t * 16 + (l & 15);
        float w = W[(size_t)k * NS + n];
        ushort_t h = f2bf(w);
        hs[j] = h;
        ls[j] = f2bf(w - bf2f(h));
    }
    #pragma unroll
    for (int j = 0; j < 8; ++j) {
        Hi[(size_t)tid * 8 + j] = hs[j];
        Lo[(size_t)tid * 8 + j] = ls[j];
    }
}

// ---------------------------------------------------------------------------
// MFMA dual GEMM (split-bf16, fp32-grade):
//   S[M,NS]  = X @ Ws + bias  (fp32 out)
//   Zb[M,NS] = X @ Wn         (bf16 out)
// X fp32 row-major, split to hi/lo bf16 in-register. Weights pre-packed.
// Block: 256 thr = 4 waves; wave owns 32 rows (2 m-tiles); block = 128 rows.
// No LDS, no barriers. x ~= hi+lo; x*w ~= hi*hi + lo*hi + hi*lo.
// ---------------------------------------------------------------------------
template <int K, int NS>
__global__ __launch_bounds__(256) void mfma_gemm(const float* __restrict__ X,
                                                 const ushort_t* __restrict__ BsHi,
                                                 const ushort_t* __restrict__ BsLo,
                                                 const ushort_t* __restrict__ BnHi,
                                                 const ushort_t* __restrict__ BnLo,
                                                 const float* __restrict__ bias,
                                                 float* __restrict__ S,
                                                 ushort_t* __restrict__ Zb,
                                                 int M) {
    constexpr int KS = K / 32;      // mfma k-steps
    constexpr int NT = NS / 16;     // n-tiles
    int tid = threadIdx.x;
    int lane = tid & 63, w = tid >> 6;
    int baseM = blockIdx.x * 128 + w * 32;
    int rIn = lane & 15, q = lane >> 4;

    // ---- load + split all A fragments for this wave's 32 rows ----
    short8 Ahi[KS][2], Alo[KS][2];
    #pragma unroll
    for (int s = 0; s < KS; ++s) {
        #pragma unroll
        for (int mt = 0; mt < 2; ++mt) {
            int gm = baseM + mt * 16 + rIn;
            if (gm < M) {
                split8(&X[(size_t)gm * K + s * 32 + q * 8], Ahi[s][mt], Alo[s][mt]);
            } else {
                #pragma unroll
                for (int j = 0; j < 8; ++j) { Ahi[s][mt][j] = 0; Alo[s][mt][j] = 0; }
            }
        }
    }

    // ---- loop n-tiles; stream B frags from L2; 12 MFMA per (s,t) ----
    for (int t = 0; t < NT; ++t) {
        f32x4 aS0 = {0.f, 0.f, 0.f, 0.f}, aS1 = {0.f, 0.f, 0.f, 0.f};
        f32x4 aZ0 = {0.f, 0.f, 0.f, 0.f}, aZ1 = {0.f, 0.f, 0.f, 0.f};
        #pragma unroll
        for (int s = 0; s < KS; ++s) {
            size_t fo = ((size_t)(s * NT + t) * 64 + lane) * 8;
            short8 bsh = *(const short8*)&BsHi[fo];
            short8 bsl = *(const short8*)&BsLo[fo];
            short8 bnh = *(const short8*)&BnHi[fo];
            short8 bnl = *(const short8*)&BnLo[fo];
            aS0 = __builtin_amdgcn_mfma_f32_16x16x32_bf16(Ahi[s][0], bsh, aS0, 0, 0, 0);
            aS0 = __builtin_amdgcn_mfma_f32_16x16x32_bf16(Alo[s][0], bsh, aS0, 0, 0, 0);
            aS0 = __builtin_amdgcn_mfma_f32_16x16x32_bf16(Ahi[s][0], bsl, aS0, 0, 0, 0);
            aS1 = __builtin_amdgcn_mfma_f32_16x16x32_bf16(Ahi[s][1], bsh, aS1, 0, 0, 0);
            aS1 = __builtin_amdgcn_mfma_f32_16x16x32_bf16(Alo[s][1], bsh, aS1, 0, 0, 0);
            aS1 = __builtin_amdgcn_mfma_f32_16x16x32_bf16(Ahi[s][1], bsl, aS1, 0, 0, 0);
            aZ0 = __builtin_amdgcn_mfma_f32_16x16x32_bf16(Ahi[s][0], bnh, aZ0, 0, 0, 0);
            aZ0 = __builtin_amdgcn_mfma_f32_16x16x32_bf16(Alo[s][0], bnh, aZ0, 0, 0, 0);
            aZ0 = __builtin_amdgcn_mfma_f32_16x16x32_bf16(Ahi[s][0], bnl, aZ0, 0, 0, 0);
            aZ1 = __builtin_amdgcn_mfma_f32_16x16x32_bf16(Ahi[s][1], bnh, aZ1, 0, 0, 0);
            aZ1 = __builtin_amdgcn_mfma_f32_16x16x32_bf16(Alo[s][1], bnh, aZ1, 0, 0, 0);
            aZ1 = __builtin_amdgcn_mfma_f32_16x16x32_bf16(Ahi[s][1], bnl, aZ1, 0, 0, 0);
        }
        // epilogue: C/D layout col = lane&15, row = (lane>>4)*4 + reg
        int col = t * 16 + rIn;
        float bv = bias[col];
        #pragma unroll
        for (int mt = 0; mt < 2; ++mt) {
            f32x4 aS = mt ? aS1 : aS0;
            f32x4 aZ = mt ? aZ1 : aZ0;
            #pragma unroll
            for (int r = 0; r < 4; ++r) {
                int gm = baseM + mt * 16 + q * 4 + r;
                if (gm < M) {
                    S[(size_t)gm * NS + col]  = aS[r] + bv;
                    Zb[(size_t)gm * NS + col] = f2bf(aZ[r]);
                }
            }
        }
    }
}

// ---------------------------------------------------------------------------
// Aggregate with bf16 Z: out[n,f] = act( S[n,f] + inv_deg[n]*sum Z[src,f] )
// Each lane covers 4 features (uint2 = 4 bf16). ACT: 0 = relu, 1 = softmax(D=64)
// ---------------------------------------------------------------------------
template <int D, int ACT>
__global__ __launch_bounds__(256) void agg_kernel(const float* __restrict__ S,
                                                  const uint2* __restrict__ Zu,
                                                  const int* __restrict__ row_ptr,
                                                  const int* __restrict__ edge_src,
                                                  const float* __restrict__ inv_deg,
                                                  float* __restrict__ out, int N) {
    constexpr int G  = D / 4;          // lanes per node
    constexpr int NG = 256 / G;        // nodes per block
    int tid = threadIdx.x;
    int g = tid / G, f4 = tid % G;
    int n = blockIdx.x * NG + g;
    if (n >= N) return;
    int beg = row_ptr[n], end = row_ptr[n + 1];

    float a0[4] = {0, 0, 0, 0}, a1[4] = {0, 0, 0, 0};
    float a2[4] = {0, 0, 0, 0}, a3[4] = {0, 0, 0, 0};
#define ACC(u, a)                                                              \
    a[0] += __uint_as_float((u).x << 16);                                      \
    a[1] += __uint_as_float((u).x & 0xFFFF0000u);                              \
    a[2] += __uint_as_float((u).y << 16);                                      \
    a[3] += __uint_as_float((u).y & 0xFFFF0000u);
    int j = beg;
    for (; j + 3 < end; j += 4) {
        int s0 = edge_src[j + 0], s1 = edge_src[j + 1];
        int s2 = edge_src[j + 2], s3 = edge_src[j + 3];
        uint2 u0 = Zu[(size_t)s0 * G + f4];
        uint2 u1 = Zu[(size_t)s1 * G + f4];
        uint2 u2 = Zu[(size_t)s2 * G + f4];
        uint2 u3 = Zu[(size_t)s3 * G + f4];
        ACC(u0, a0) ACC(u1, a1) ACC(u2, a2) ACC(u3, a3)
    }
    for (; j < end; ++j) {
        uint2 u = Zu[(size_t)edge_src[j] * G + f4];
        ACC(u, a0)
    }
#undef ACC
    float id = inv_deg[n];
    float4 sv = ((const float4*)(S + (size_t)n * D))[f4];
    float v[4];
    v[0] = sv.x + id * ((a0[0] + a1[0]) + (a2[0] + a3[0]));
    v[1] = sv.y + id * ((a0[1] + a1[1]) + (a2[1] + a3[1]));
    v[2] = sv.z + id * ((a0[2] + a1[2]) + (a2[2] + a3[2]));
    v[3] = sv.w + id * ((a0[3] + a1[3]) + (a2[3] + a3[3]));

    float4 o;
    if (ACT == 0) {
        o.x = fmaxf(v[0], 0.f); o.y = fmaxf(v[1], 0.f);
        o.z = fmaxf(v[2], 0.f); o.w = fmaxf(v[3], 0.f);
    } else {
        // softmax across G=16 lanes x 4 vals
        float m = fmaxf(fmaxf(v[0], v[1]), fmaxf(v[2], v[3]));
        #pragma unroll
        for (int off = 8; off > 0; off >>= 1) m = fmaxf(m, __shfl_xor(m, off, 16));
        float e0 = __expf(v[0] - m), e1 = __expf(v[1] - m);
        float e2 = __expf(v[2] - m), e3 = __expf(v[3] - m);
        float s = (e0 + e1) + (e2 + e3);
        #pragma unroll
        for (int off = 8; off > 0; off >>= 1) s += __shfl_xor(s, off, 16);
        float inv = 1.0f / s;
        o.x = e0 * inv; o.y = e1 * inv; o.z = e2 * inv; o.w = e3 * inv;
    }
    ((float4*)(out + (size_t)n * D))[f4] = o;
}

// ---------------------------------------------------------------------------
extern "C" void kernel_launch(void* const* d_in, const int* in_sizes, int n_in,
                              void* d_out, int out_size, void* d_ws, size_t ws_size,
                              hipStream_t stream) {
    const float* in_feat = (const float*)d_in[0];
    const int*   src     = (const int*)d_in[1];
    const int*   dst     = (const int*)d_in[2];
    const float* w1s = (const float*)d_in[3];
    const float* w1n = (const float*)d_in[4];
    const float* b1  = (const float*)d_in[5];
    const float* w2s = (const float*)d_in[6];
    const float* w2n = (const float*)d_in[7];
    const float* b2  = (const float*)d_in[8];
    const float* w3s = (const float*)d_in[9];
    const float* w3n = (const float*)d_in[10];
    const float* b3  = (const float*)d_in[11];

    const int N = N_NODES;
    const int E = in_sizes[1];

    char* p = (char*)d_ws;
    auto carve = [&](size_t bytes) -> char* {
        char* q = p;
        p += (bytes + 511) & ~(size_t)511;
        return q;
    };
    float*    S        = (float*)   carve((size_t)N * 128 * sizeof(float));
    ushort_t* Zb       = (ushort_t*)carve((size_t)N * 128 * sizeof(ushort_t));
    float*    H        = (float*)   carve((size_t)N * 128 * sizeof(float));
    int*      edge_src = (int*)     carve((size_t)E * sizeof(int));
    int*      row_ptr  = (int*)     carve((size_t)(N + 1) * sizeof(int));
    int*      cursor   = (int*)     carve((size_t)N * sizeof(int));
    int*      deg      = (int*)     carve((size_t)N * sizeof(int));
    float*    invd     = (float*)   carve((size_t)N * sizeof(float));
    int*      partials = (int*)     carve(256 * sizeof(int));
    // packed weights (hi/lo per matrix)
    ushort_t* P1sH = (ushort_t*)carve(128 * 128 * 2); ushort_t* P1sL = (ushort_t*)carve(128 * 128 * 2);
    ushort_t* P1nH = (ushort_t*)carve(128 * 128 * 2); ushort_t* P1nL = (ushort_t*)carve(128 * 128 * 2);
    ushort_t* P2sH = (ushort_t*)carve(128 * 64 * 2);  ushort_t* P2sL = (ushort_t*)carve(128 * 64 * 2);
    ushort_t* P2nH = (ushort_t*)carve(128 * 64 * 2);  ushort_t* P2nL = (ushort_t*)carve(128 * 64 * 2);
    ushort_t* P3sH = (ushort_t*)carve(64 * 64 * 2);   ushort_t* P3sL = (ushort_t*)carve(64 * 64 * 2);
    ushort_t* P3nH = (ushort_t*)carve(64 * 64 * 2);   ushort_t* P3nL = (ushort_t*)carve(64 * 64 * 2);

    // ---- weight packing (single launch, 28 blocks) ----
    pack_all<<<28, 256, 0, stream>>>(w1s, w1n, w2s, w2n, w3s, w3n,
                                     P1sH, P1sL, P1nH, P1nL,
                                     P2sH, P2sL, P2nH, P2nL,
                                     P3sH, P3sL, P3nH, P3nL);

    // ---- CSR build ----
    hipMemsetAsync(deg, 0, (size_t)N * sizeof(int), stream);
    hist_kernel<<<(E + 255) / 256, 256, 0, stream>>>(dst, deg, E);
    const int NB = (N + 1023) / 1024;   // 98 segments
    scan_partial_sums<<<NB, 256, 0, stream>>>(deg, partials, N);
    scan_partials<<<1, 256, 0, stream>>>(partials, NB, row_ptr, N);
    scan_emit<<<NB, 256, 0, stream>>>(deg, partials, row_ptr, cursor, invd, N);
    fill_part<<<FILL_GROUPS * FILL_BPG, 256, 0, stream>>>(src, dst, cursor, edge_src, E, N);

    const int GB = (N + 127) / 128;   // 782 row blocks

    // ---- Layer 1: 128 -> 128, relu ----
    mfma_gemm<128, 128><<<GB, 256, 0, stream>>>(in_feat, P1sH, P1sL, P1nH, P1nL, b1, S, Zb, N);
    agg_kernel<128, 0><<<(N + 7) / 8, 256, 0, stream>>>(S, (const uint2*)Zb,
                                                        row_ptr, edge_src, invd, H, N);

    // ---- Layer 2: 128 -> 64, relu ----
    mfma_gemm<128, 64><<<GB, 256, 0, stream>>>(H, P2sH, P2sL, P2nH, P2nL, b2, S, Zb, N);
    agg_kernel<64, 0><<<(N + 15) / 16, 256, 0, stream>>>(S, (const uint2*)Zb,
                                                         row_ptr, edge_src, invd, H, N);

    // ---- Layer 3: 64 -> 64, softmax ----
    mfma_gemm<64, 64><<<GB, 256, 0, stream>>>(H, P3sH, P3sL, P3nH, P3nL, b3, S, Zb, N);
    agg_kernel<64, 1><<<(N + 15) / 16, 256, 0, stream>>>(S, (const uint2*)Zb,
                                                         row_ptr, edge_src, invd,
                                                         (float*)d_out, N);
}

// Round 6
// 517.397 us; speedup vs baseline: 1.6030x; 1.0056x over previous
//
#include <hip/hip_runtime.h>
#include <hip/hip_bf16.h>

#define N_NODES 100000

typedef unsigned short ushort_t;
typedef __attribute__((ext_vector_type(8))) short short8;
typedef __attribute__((ext_vector_type(4))) float f32x4;

// ---------------------------------------------------------------------------
// helpers
// ---------------------------------------------------------------------------
static __device__ __forceinline__ ushort_t f2bf(float f) {
    unsigned u = __float_as_uint(f);
    unsigned r = u + 0x7FFFu + ((u >> 16) & 1u);   // round-to-nearest-even
    return (ushort_t)(r >> 16);
}
static __device__ __forceinline__ float bf2f(ushort_t h) {
    return __uint_as_float(((unsigned)h) << 16);
}

// split 8 contiguous fp32 into hi/lo bf16 fragments
static __device__ __forceinline__ void split8(const float* __restrict__ xp,
                                              short8& hi, short8& lo) {
    float4 x0 = *(const float4*)xp;
    float4 x1 = *(const float4*)(xp + 4);
    float xs[8] = {x0.x, x0.y, x0.z, x0.w, x1.x, x1.y, x1.z, x1.w};
    #pragma unroll
    for (int j = 0; j < 8; ++j) {
        ushort_t h = f2bf(xs[j]);
        hi[j] = (short)h;
        lo[j] = (short)f2bf(xs[j] - bf2f(h));
    }
}

// ---------------------------------------------------------------------------
// CSR build: histogram -> 3-phase multi-block scan -> XCD-partitioned fill
// ---------------------------------------------------------------------------
__global__ __launch_bounds__(256) void hist_kernel(const int* __restrict__ dst,
                                                   int* __restrict__ deg, int E) {
    int e = blockIdx.x * 256 + threadIdx.x;
    if (e < E) atomicAdd(&deg[__builtin_nontemporal_load(&dst[e])], 1);
}

// phase 1: per-block (1024-elem segment) total
__global__ __launch_bounds__(256) void scan_partial_sums(const int* __restrict__ deg,
                                                         int* __restrict__ partials, int N) {
    __shared__ int wsums[4];
    int tid = threadIdx.x, lane = tid & 63, wv = tid >> 6;
    int i0 = blockIdx.x * 1024 + tid * 4;
    int s = 0;
    #pragma unroll
    for (int j = 0; j < 4; ++j) {
        int i = i0 + j;
        if (i < N) s += deg[i];
    }
    #pragma unroll
    for (int off = 32; off > 0; off >>= 1) s += __shfl_xor(s, off, 64);
    if (lane == 0) wsums[wv] = s;
    __syncthreads();
    if (tid == 0)
        partials[blockIdx.x] = wsums[0] + wsums[1] + wsums[2] + wsums[3];
}

// phase 2: single block scans NB (<=256) partials -> exclusive, writes row_ptr[N]
__global__ __launch_bounds__(256) void scan_partials(int* __restrict__ partials, int NB,
                                                     int* __restrict__ row_ptr, int N) {
    __shared__ int wsums[4];
    int tid = threadIdx.x, lane = tid & 63, wv = tid >> 6;
    int v = (tid < NB) ? partials[tid] : 0;
    int x = v;
    #pragma unroll
    for (int off = 1; off < 64; off <<= 1) {
        int y = __shfl_up(x, off, 64);
        if (lane >= off) x += y;
    }
    if (lane == 63) wsums[wv] = x;
    __syncthreads();
    int woff = 0;
    for (int w = 0; w < wv; ++w) woff += wsums[w];
    int incl = x + woff;
    if (tid < NB) partials[tid] = incl - v;          // exclusive
    if (tid == NB - 1) row_ptr[N] = incl;            // grand total
}

// phase 3: re-read segment, local scan + block offset, emit row_ptr/cursor/invd
__global__ __launch_bounds__(256) void scan_emit(const int* __restrict__ deg,
                                                 const int* __restrict__ partials,
                                                 int* __restrict__ row_ptr,
                                                 int* __restrict__ cursor,
                                                 float* __restrict__ inv_deg, int N) {
    __shared__ int wsums[4];
    int tid = threadIdx.x, lane = tid & 63, wv = tid >> 6;
    int i0 = blockIdx.x * 1024 + tid * 4;
    int d[4];
    #pragma unroll
    for (int j = 0; j < 4; ++j) {
        int i = i0 + j;
        d[j] = (i < N) ? deg[i] : 0;
    }
    int s = d[0] + d[1] + d[2] + d[3];
    int x = s;
    #pragma unroll
    for (int off = 1; off < 64; off <<= 1) {
        int y = __shfl_up(x, off, 64);
        if (lane >= off) x += y;
    }
    if (lane == 63) wsums[wv] = x;
    __syncthreads();
    int woff = 0;
    for (int w = 0; w < wv; ++w) woff += wsums[w];
    int run = partials[blockIdx.x] + woff + x - s;   // exclusive prefix of elem i0
    #pragma unroll
    for (int j = 0; j < 4; ++j) {
        int i = i0 + j;
        if (i < N) {
            row_ptr[i] = run;
            cursor[i]  = run;
            inv_deg[i] = 1.0f / (float)(d[j] > 0 ? d[j] : 1);
            run += d[j];
        }
    }
}

// XCD-partitioned fill: group g = blockIdx&7 (maps ~to XCD g) handles dst range
// [lo,hi). Its writes land in a contiguous ~E/8*4B region resident in that
// XCD's L2 so lines fill before writeback. dst/src reads are NON-TEMPORAL so
// the streaming re-reads don't evict the write slice (R5 lesson: they did).
#define FILL_GROUPS 8
#define FILL_BPG    128
__global__ __launch_bounds__(256) void fill_part(const int* __restrict__ src,
                                                 const int* __restrict__ dst,
                                                 int* __restrict__ cursor,
                                                 int* __restrict__ edge_src,
                                                 int E, int N) {
    int g    = blockIdx.x & (FILL_GROUPS - 1);
    int bInG = blockIdx.x >> 3;
    int lo = (int)((long long)N * g / FILL_GROUPS);
    int hi = (int)((long long)N * (g + 1) / FILL_GROUPS);
    int stride = FILL_BPG * 256;
    for (int e = bInG * 256 + threadIdx.x; e < E; e += stride) {
        int d = __builtin_nontemporal_load(&dst[e]);
        if (d >= lo && d < hi) {
            int sv = __builtin_nontemporal_load(&src[e]);
            int p = atomicAdd(&cursor[d], 1);
            edge_src[p] = sv;
        }
    }
}

// ---------------------------------------------------------------------------
// Weight pre-pack (all 6 matrices in ONE launch):
// W[K x NS] fp32 row-major -> MFMA B-fragment order, hi/lo bf16.
// Fragment (s = k-step, t = n-tile): lane l, j in 0..7 holds
//   W[k = s*32 + (l>>4)*8 + j][n = t*16 + (l&15)]
// packed at element offset ((s*NT + t)*64 + l)*8 + j.
// ---------------------------------------------------------------------------
__global__ __launch_bounds__(256) void pack_all(
        const float* __restrict__ W0, const float* __restrict__ W1,
        const float* __restrict__ W2, const float* __restrict__ W3,
        const float* __restrict__ W4, const float* __restrict__ W5,
        ushort_t* H0, ushort_t* L0, ushort_t* H1, ushort_t* L1,
        ushort_t* H2, ushort_t* L2, ushort_t* H3, ushort_t* L3,
        ushort_t* H4, ushort_t* L4, ushort_t* H5, ushort_t* L5) {
    int b = blockIdx.x;
    const float* W; ushort_t* Hi; ushort_t* Lo; int K, NS, base;
    if (b < 8)       { W = W0; Hi = H0; Lo = L0; K = 128; NS = 128; base = 0;  }
    else if (b < 16) { W = W1; Hi = H1; Lo = L1; K = 128; NS = 128; base = 8;  }
    else if (b < 20) { W = W2; Hi = H2; Lo = L2; K = 128; NS = 64;  base = 16; }
    else if (b < 24) { W = W3; Hi = H3; Lo = L3; K = 128; NS = 64;  base = 20; }
    else if (b < 26) { W = W4; Hi = H4; Lo = L4; K = 64;  NS = 64;  base = 24; }
    else             { W = W5; Hi = H5; Lo = L5; K = 64;  NS = 64;  base = 26; }
    int tid = (b - base) * 256 + threadIdx.x;
    if (tid >= (K * NS) / 8) return;
    int l  = tid & 63;
    int fl = tid >> 6;
    int NT = NS / 16;
    int t = fl % NT, s = fl / NT;
    ushort_t hs[8], ls[8];
    #pragma unroll
    for (int j = 0; j < 8; ++j) {
        int k = s * 32 + (l >> 4) * 8 + j;
        int n = t * 16 + (l & 15);
        float w = W[(size_t)k * NS + n];
        ushort_t h = f2bf(w);
        hs[j] = h;
        ls[j] = f2bf(w - bf2f(h));
    }
    #pragma unroll
    for (int j = 0; j < 8; ++j) {
        Hi[(size_t)tid * 8 + j] = hs[j];
        Lo[(size_t)tid * 8 + j] = ls[j];
    }
}

// ---------------------------------------------------------------------------
// MFMA dual GEMM (split-bf16, fp32-grade):
//   S[M,NS]  = X @ Ws + bias  (fp32 out)
//   Zb[M,NS] = X @ Wn         (bf16 out)
// X fp32 row-major, split to hi/lo bf16 in-register. Weights pre-packed.
// Block: 256 thr = 4 waves; wave owns 32 rows (2 m-tiles); block = 128 rows.
// No LDS, no barriers. x ~= hi+lo; x*w ~= hi*hi + lo*hi + hi*lo.
// ---------------------------------------------------------------------------
template <int K, int NS>
__global__ __launch_bounds__(256) void mfma_gemm(const float* __restrict__ X,
                                                 const ushort_t* __restrict__ BsHi,
                                                 const ushort_t* __restrict__ BsLo,
                                                 const ushort_t* __restrict__ BnHi,
                                                 const ushort_t* __restrict__ BnLo,
                                                 const float* __restrict__ bias,
                                                 float* __restrict__ S,
                                                 ushort_t* __restrict__ Zb,
                                                 int M) {
    constexpr int KS = K / 32;      // mfma k-steps
    constexpr int NT = NS / 16;     // n-tiles
    int tid = threadIdx.x;
    int lane = tid & 63, w = tid >> 6;
    int baseM = blockIdx.x * 128 + w * 32;
    int rIn = lane & 15, q = lane >> 4;

    // ---- load + split all A fragments for this wave's 32 rows ----
    short8 Ahi[KS][2], Alo[KS][2];
    #pragma unroll
    for (int s = 0; s < KS; ++s) {
        #pragma unroll
        for (int mt = 0; mt < 2; ++mt) {
            int gm = baseM + mt * 16 + rIn;
            if (gm < M) {
                split8(&X[(size_t)gm * K + s * 32 + q * 8], Ahi[s][mt], Alo[s][mt]);
            } else {
                #pragma unroll
                for (int j = 0; j < 8; ++j) { Ahi[s][mt][j] = 0; Alo[s][mt][j] = 0; }
            }
        }
    }

    // ---- loop n-tiles; stream B frags from L2; 12 MFMA per (s,t) ----
    for (int t = 0; t < NT; ++t) {
        f32x4 aS0 = {0.f, 0.f, 0.f, 0.f}, aS1 = {0.f, 0.f, 0.f, 0.f};
        f32x4 aZ0 = {0.f, 0.f, 0.f, 0.f}, aZ1 = {0.f, 0.f, 0.f, 0.f};
        #pragma unroll
        for (int s = 0; s < KS; ++s) {
            size_t fo = ((size_t)(s * NT + t) * 64 + lane) * 8;
            short8 bsh = *(const short8*)&BsHi[fo];
            short8 bsl = *(const short8*)&BsLo[fo];
            short8 bnh = *(const short8*)&BnHi[fo];
            short8 bnl = *(const short8*)&BnLo[fo];
            aS0 = __builtin_amdgcn_mfma_f32_16x16x32_bf16(Ahi[s][0], bsh, aS0, 0, 0, 0);
            aS0 = __builtin_amdgcn_mfma_f32_16x16x32_bf16(Alo[s][0], bsh, aS0, 0, 0, 0);
            aS0 = __builtin_amdgcn_mfma_f32_16x16x32_bf16(Ahi[s][0], bsl, aS0, 0, 0, 0);
            aS1 = __builtin_amdgcn_mfma_f32_16x16x32_bf16(Ahi[s][1], bsh, aS1, 0, 0, 0);
            aS1 = __builtin_amdgcn_mfma_f32_16x16x32_bf16(Alo[s][1], bsh, aS1, 0, 0, 0);
            aS1 = __builtin_amdgcn_mfma_f32_16x16x32_bf16(Ahi[s][1], bsl, aS1, 0, 0, 0);
            aZ0 = __builtin_amdgcn_mfma_f32_16x16x32_bf16(Ahi[s][0], bnh, aZ0, 0, 0, 0);
            aZ0 = __builtin_amdgcn_mfma_f32_16x16x32_bf16(Alo[s][0], bnh, aZ0, 0, 0, 0);
            aZ0 = __builtin_amdgcn_mfma_f32_16x16x32_bf16(Ahi[s][0], bnl, aZ0, 0, 0, 0);
            aZ1 = __builtin_amdgcn_mfma_f32_16x16x32_bf16(Ahi[s][1], bnh, aZ1, 0, 0, 0);
            aZ1 = __builtin_amdgcn_mfma_f32_16x16x32_bf16(Alo[s][1], bnh, aZ1, 0, 0, 0);
            aZ1 = __builtin_amdgcn_mfma_f32_16x16x32_bf16(Ahi[s][1], bnl, aZ1, 0, 0, 0);
        }
        // epilogue: C/D layout col = lane&15, row = (lane>>4)*4 + reg
        int col = t * 16 + rIn;
        float bv = bias[col];
        #pragma unroll
        for (int mt = 0; mt < 2; ++mt) {
            f32x4 aS = mt ? aS1 : aS0;
            f32x4 aZ = mt ? aZ1 : aZ0;
            #pragma unroll
            for (int r = 0; r < 4; ++r) {
                int gm = baseM + mt * 16 + q * 4 + r;
                if (gm < M) {
                    S[(size_t)gm * NS + col]  = aS[r] + bv;
                    Zb[(size_t)gm * NS + col] = f2bf(aZ[r]);
                }
            }
        }
    }
}

// ---------------------------------------------------------------------------
// Aggregate with bf16 Z: out[n,f] = act( S[n,f] + inv_deg[n]*sum Z[src,f] )
// Each lane covers 4 features (uint2 = 4 bf16). ACT: 0 = relu, 1 = softmax(D=64)
// ---------------------------------------------------------------------------
template <int D, int ACT>
__global__ __launch_bounds__(256) void agg_kernel(const float* __restrict__ S,
                                                  const uint2* __restrict__ Zu,
                                                  const int* __restrict__ row_ptr,
                                                  const int* __restrict__ edge_src,
                                                  const float* __restrict__ inv_deg,
                                                  float* __restrict__ out, int N) {
    constexpr int G  = D / 4;          // lanes per node
    constexpr int NG = 256 / G;        // nodes per block
    int tid = threadIdx.x;
    int g = tid / G, f4 = tid % G;
    int n = blockIdx.x * NG + g;
    if (n >= N) return;
    int beg = row_ptr[n], end = row_ptr[n + 1];

    float a0[4] = {0, 0, 0, 0}, a1[4] = {0, 0, 0, 0};
    float a2[4] = {0, 0, 0, 0}, a3[4] = {0, 0, 0, 0};
#define ACC(u, a)                                                              \
    a[0] += __uint_as_float((u).x << 16);                                      \
    a[1] += __uint_as_float((u).x & 0xFFFF0000u);                              \
    a[2] += __uint_as_float((u).y << 16);                                      \
    a[3] += __uint_as_float((u).y & 0xFFFF0000u);
    int j = beg;
    for (; j + 3 < end; j += 4) {
        int s0 = edge_src[j + 0], s1 = edge_src[j + 1];
        int s2 = edge_src[j + 2], s3 = edge_src[j + 3];
        uint2 u0 = Zu[(size_t)s0 * G + f4];
        uint2 u1 = Zu[(size_t)s1 * G + f4];
        uint2 u2 = Zu[(size_t)s2 * G + f4];
        uint2 u3 = Zu[(size_t)s3 * G + f4];
        ACC(u0, a0) ACC(u1, a1) ACC(u2, a2) ACC(u3, a3)
    }
    for (; j < end; ++j) {
        uint2 u = Zu[(size_t)edge_src[j] * G + f4];
        ACC(u, a0)
    }
#undef ACC
    float id = inv_deg[n];
    float4 sv = ((const float4*)(S + (size_t)n * D))[f4];
    float v[4];
    v[0] = sv.x + id * ((a0[0] + a1[0]) + (a2[0] + a3[0]));
    v[1] = sv.y + id * ((a0[1] + a1[1]) + (a2[1] + a3[1]));
    v[2] = sv.z + id * ((a0[2] + a1[2]) + (a2[2] + a3[2]));
    v[3] = sv.w + id * ((a0[3] + a1[3]) + (a2[3] + a3[3]));

    float4 o;
    if (ACT == 0) {
        o.x = fmaxf(v[0], 0.f); o.y = fmaxf(v[1], 0.f);
        o.z = fmaxf(v[2], 0.f); o.w = fmaxf(v[3], 0.f);
    } else {
        // softmax across G=16 lanes x 4 vals
        float m = fmaxf(fmaxf(v[0], v[1]), fmaxf(v[2], v[3]));
        #pragma unroll
        for (int off = 8; off > 0; off >>= 1) m = fmaxf(m, __shfl_xor(m, off, 16));
        float e0 = __expf(v[0] - m), e1 = __expf(v[1] - m);
        float e2 = __expf(v[2] - m), e3 = __expf(v[3] - m);
        float s = (e0 + e1) + (e2 + e3);
        #pragma unroll
        for (int off = 8; off > 0; off >>= 1) s += __shfl_xor(s, off, 16);
        float inv = 1.0f / s;
        o.x = e0 * inv; o.y = e1 * inv; o.z = e2 * inv; o.w = e3 * inv;
    }
    ((float4*)(out + (size_t)n * D))[f4] = o;
}

// ---------------------------------------------------------------------------
extern "C" void kernel_launch(void* const* d_in, const int* in_sizes, int n_in,
                              void* d_out, int out_size, void* d_ws, size_t ws_size,
                              hipStream_t stream) {
    const float* in_feat = (const float*)d_in[0];
    const int*   src     = (const int*)d_in[1];
    const int*   dst     = (const int*)d_in[2];
    const float* w1s = (const float*)d_in[3];
    const float* w1n = (const float*)d_in[4];
    const float* b1  = (const float*)d_in[5];
    const float* w2s = (const float*)d_in[6];
    const float* w2n = (const float*)d_in[7];
    const float* b2  = (const float*)d_in[8];
    const float* w3s = (const float*)d_in[9];
    const float* w3n = (const float*)d_in[10];
    const float* b3  = (const float*)d_in[11];

    const int N = N_NODES;
    const int E = in_sizes[1];

    char* p = (char*)d_ws;
    auto carve = [&](size_t bytes) -> char* {
        char* q = p;
        p += (bytes + 511) & ~(size_t)511;
        return q;
    };
    float*    S        = (float*)   carve((size_t)N * 128 * sizeof(float));
    ushort_t* Zb       = (ushort_t*)carve((size_t)N * 128 * sizeof(ushort_t));
    float*    H        = (float*)   carve((size_t)N * 128 * sizeof(float));
    int*      edge_src = (int*)     carve((size_t)E * sizeof(int));
    int*      row_ptr  = (int*)     carve((size_t)(N + 1) * sizeof(int));
    int*      cursor   = (int*)     carve((size_t)N * sizeof(int));
    int*      deg      = (int*)     carve((size_t)N * sizeof(int));
    float*    invd     = (float*)   carve((size_t)N * sizeof(float));
    int*      partials = (int*)     carve(256 * sizeof(int));
    // packed weights (hi/lo per matrix)
    ushort_t* P1sH = (ushort_t*)carve(128 * 128 * 2); ushort_t* P1sL = (ushort_t*)carve(128 * 128 * 2);
    ushort_t* P1nH = (ushort_t*)carve(128 * 128 * 2); ushort_t* P1nL = (ushort_t*)carve(128 * 128 * 2);
    ushort_t* P2sH = (ushort_t*)carve(128 * 64 * 2);  ushort_t* P2sL = (ushort_t*)carve(128 * 64 * 2);
    ushort_t* P2nH = (ushort_t*)carve(128 * 64 * 2);  ushort_t* P2nL = (ushort_t*)carve(128 * 64 * 2);
    ushort_t* P3sH = (ushort_t*)carve(64 * 64 * 2);   ushort_t* P3sL = (ushort_t*)carve(64 * 64 * 2);
    ushort_t* P3nH = (ushort_t*)carve(64 * 64 * 2);   ushort_t* P3nL = (ushort_t*)carve(64 * 64 * 2);

    // ---- weight packing (single launch, 28 blocks) ----
    pack_all<<<28, 256, 0, stream>>>(w1s, w1n, w2s, w2n, w3s, w3n,
                                     P1sH, P1sL, P1nH, P1nL,
                                     P2sH, P2sL, P2nH, P2nL,
                                     P3sH, P3sL, P3nH, P3nL);

    // ---- CSR build ----
    hipMemsetAsync(deg, 0, (size_t)N * sizeof(int), stream);
    hist_kernel<<<(E + 255) / 256, 256, 0, stream>>>(dst, deg, E);
    const int NB = (N + 1023) / 1024;   // 98 segments
    scan_partial_sums<<<NB, 256, 0, stream>>>(deg, partials, N);
    scan_partials<<<1, 256, 0, stream>>>(partials, NB, row_ptr, N);
    scan_emit<<<NB, 256, 0, stream>>>(deg, partials, row_ptr, cursor, invd, N);
    fill_part<<<FILL_GROUPS * FILL_BPG, 256, 0, stream>>>(src, dst, cursor, edge_src, E, N);

    const int GB = (N + 127) / 128;   // 782 row blocks

    // ---- Layer 1: 128 -> 128, relu ----
    mfma_gemm<128, 128><<<GB, 256, 0, stream>>>(in_feat, P1sH, P1sL, P1nH, P1nL, b1, S, Zb, N);
    agg_kernel<128, 0><<<(N + 7) / 8, 256, 0, stream>>>(S, (const uint2*)Zb,
                                                        row_ptr, edge_src, invd, H, N);

    // ---- Layer 2: 128 -> 64, relu ----
    mfma_gemm<128, 64><<<GB, 256, 0, stream>>>(H, P2sH, P2sL, P2nH, P2nL, b2, S, Zb, N);
    agg_kernel<64, 0><<<(N + 15) / 16, 256, 0, stream>>>(S, (const uint2*)Zb,
                                                         row_ptr, edge_src, invd, H, N);

    // ---- Layer 3: 64 -> 64, softmax ----
    mfma_gemm<64, 64><<<GB, 256, 0, stream>>>(H, P3sH, P3sL, P3nH, P3nL, b3, S, Zb, N);
    agg_kernel<64, 1><<<(N + 15) / 16, 256, 0, stream>>>(S, (const uint2*)Zb,
                                                         row_ptr, edge_src, invd,
                                                         (float*)d_out, N);
}

// Round 8
// 504.774 us; speedup vs baseline: 1.6431x; 1.0250x over previous
//
#include <hip/hip_runtime.h>
#include <hip/hip_bf16.h>

#define N_NODES 100000

typedef unsigned short ushort_t;
typedef __attribute__((ext_vector_type(8))) short short8;
typedef __attribute__((ext_vector_type(4))) float f32x4;

// ---------------------------------------------------------------------------
// helpers
// ---------------------------------------------------------------------------
static __device__ __forceinline__ ushort_t f2bf(float f) {
    unsigned u = __float_as_uint(f);
    unsigned r = u + 0x7FFFu + ((u >> 16) & 1u);   // round-to-nearest-even
    return (ushort_t)(r >> 16);
}
static __device__ __forceinline__ float bf2f(ushort_t h) {
    return __uint_as_float(((unsigned)h) << 16);
}

// split 8 contiguous fp32 into hi/lo bf16 fragments
static __device__ __forceinline__ void split8(const float* __restrict__ xp,
                                              short8& hi, short8& lo) {
    float4 x0 = *(const float4*)xp;
    float4 x1 = *(const float4*)(xp + 4);
    float xs[8] = {x0.x, x0.y, x0.z, x0.w, x1.x, x1.y, x1.z, x1.w};
    #pragma unroll
    for (int j = 0; j < 8; ++j) {
        ushort_t h = f2bf(xs[j]);
        hi[j] = (short)h;
        lo[j] = (short)f2bf(xs[j] - bf2f(h));
    }
}

// ---------------------------------------------------------------------------
// CSR build: histogram -> 3-phase scan -> bucket-binning -> exclusive scatter
// ---------------------------------------------------------------------------
__global__ __launch_bounds__(256) void hist_kernel(const int* __restrict__ dst,
                                                   int* __restrict__ deg, int E) {
    int e = blockIdx.x * 256 + threadIdx.x;
    if (e < E) atomicAdd(&deg[__builtin_nontemporal_load(&dst[e])], 1);
}

// phase 1: per-block (1024-elem segment) total
__global__ __launch_bounds__(256) void scan_partial_sums(const int* __restrict__ deg,
                                                         int* __restrict__ partials, int N) {
    __shared__ int wsums[4];
    int tid = threadIdx.x, lane = tid & 63, wv = tid >> 6;
    int i0 = blockIdx.x * 1024 + tid * 4;
    int s = 0;
    #pragma unroll
    for (int j = 0; j < 4; ++j) {
        int i = i0 + j;
        if (i < N) s += deg[i];
    }
    #pragma unroll
    for (int off = 32; off > 0; off >>= 1) s += __shfl_xor(s, off, 64);
    if (lane == 0) wsums[wv] = s;
    __syncthreads();
    if (tid == 0)
        partials[blockIdx.x] = wsums[0] + wsums[1] + wsums[2] + wsums[3];
}

// phase 2: single block scans NB (<=256) partials -> exclusive, writes row_ptr[N]
__global__ __launch_bounds__(256) void scan_partials(int* __restrict__ partials, int NB,
                                                     int* __restrict__ row_ptr, int N) {
    __shared__ int wsums[4];
    int tid = threadIdx.x, lane = tid & 63, wv = tid >> 6;
    int v = (tid < NB) ? partials[tid] : 0;
    int x = v;
    #pragma unroll
    for (int off = 1; off < 64; off <<= 1) {
        int y = __shfl_up(x, off, 64);
        if (lane >= off) x += y;
    }
    if (lane == 63) wsums[wv] = x;
    __syncthreads();
    int woff = 0;
    for (int w = 0; w < wv; ++w) woff += wsums[w];
    int incl = x + woff;
    if (tid < NB) partials[tid] = incl - v;          // exclusive
    if (tid == NB - 1) row_ptr[N] = incl;            // grand total
}

// phase 3: emit row_ptr/cursor/invd; also init per-bucket cursor gcur
__global__ __launch_bounds__(256) void scan_emit(const int* __restrict__ deg,
                                                 const int* __restrict__ partials,
                                                 int* __restrict__ row_ptr,
                                                 int* __restrict__ cursor,
                                                 float* __restrict__ inv_deg,
                                                 int* __restrict__ gcur, int N) {
    __shared__ int wsums[4];
    int tid = threadIdx.x, lane = tid & 63, wv = tid >> 6;
    int i0 = blockIdx.x * 1024 + tid * 4;
    int d[4];
    #pragma unroll
    for (int j = 0; j < 4; ++j) {
        int i = i0 + j;
        d[j] = (i < N) ? deg[i] : 0;
    }
    int s = d[0] + d[1] + d[2] + d[3];
    int x = s;
    #pragma unroll
    for (int off = 1; off < 64; off <<= 1) {
        int y = __shfl_up(x, off, 64);
        if (lane >= off) x += y;
    }
    if (lane == 63) wsums[wv] = x;
    __syncthreads();
    int woff = 0;
    for (int w = 0; w < wv; ++w) woff += wsums[w];
    int run = partials[blockIdx.x] + woff + x - s;   // exclusive prefix of elem i0
    #pragma unroll
    for (int j = 0; j < 4; ++j) {
        int i = i0 + j;
        if (i < N) {
            row_ptr[i] = run;
            cursor[i]  = run;
            inv_deg[i] = 1.0f / (float)(d[j] > 0 ? d[j] : 1);
            if ((i & 255) == 0) gcur[i >> 8] = run;   // bucket staging base
            run += d[j];
        }
    }
}

// Phase A: bin (src,dst) pairs into bucket-ordered staging (bucket = dst>>8).
// Each block owns a contiguous edge chunk; reserves per-bucket runs via one
// global atomic per (block,bucket) -> every staging line written by ~one block
// -> full-line writebacks regardless of block->XCD mapping (R6 lesson).
#define MAXBUCK 512
__global__ __launch_bounds__(256) void bin_pairs(const int* __restrict__ src,
                                                 const int* __restrict__ dst,
                                                 int* __restrict__ gcur,
                                                 long long* __restrict__ staged,
                                                 int E, int NBUCK, int C) {
    __shared__ int cnt[MAXBUCK];
    int tid = threadIdx.x;
    int e0 = blockIdx.x * C;
    int e1 = min(e0 + C, E);
    for (int b = tid; b < NBUCK; b += 256) cnt[b] = 0;
    __syncthreads();
    for (int e = e0 + tid; e < e1; e += 256) {
        int d = __builtin_nontemporal_load(&dst[e]);
        atomicAdd(&cnt[d >> 8], 1);
    }
    __syncthreads();
    for (int b = tid; b < NBUCK; b += 256) {
        int c = cnt[b];
        cnt[b] = (c > 0) ? atomicAdd(&gcur[b], c) : 0;   // now LDS cursor = global pos
    }
    __syncthreads();
    for (int e = e0 + tid; e < e1; e += 256) {
        int d = __builtin_nontemporal_load(&dst[e]);
        int s = __builtin_nontemporal_load(&src[e]);
        int p = atomicAdd(&cnt[d >> 8], 1);
        staged[p] = ((long long)d << 32) | (unsigned)s;   // hi=dst, lo=src
    }
}

// Phase B: one block per bucket; scatter within a private ~16KB edge_src
// window (exclusive to this block) -> lines accumulate ~16 writes, full-line
// writeback. Reads of staged are coalesced.
__global__ __launch_bounds__(256) void scatter_bucket(const long long* __restrict__ staged,
                                                      const int* __restrict__ row_ptr,
                                                      int* __restrict__ cursor,
                                                      int* __restrict__ edge_src,
                                                      int N) {
    int b = blockIdx.x;
    int lo = b << 8;
    int hiN = min((b + 1) << 8, N);
    int gstart = row_ptr[lo];
    int gend   = row_ptr[hiN];
    for (int p = gstart + threadIdx.x; p < gend; p += 256) {
        long long pr = __builtin_nontemporal_load(&staged[p]);
        int d = (int)(pr >> 32);
        int s = (int)(pr & 0xFFFFFFFFll);
        int pos = atomicAdd(&cursor[d], 1);
        edge_src[pos] = s;
    }
}

// ---------------------------------------------------------------------------
// Weight pre-pack (all 6 matrices in ONE launch):
// W[K x NS] fp32 row-major -> MFMA B-fragment order, hi/lo bf16.
// Fragment (s = k-step, t = n-tile): lane l, j in 0..7 holds
//   W[k = s*32 + (l>>4)*8 + j][n = t*16 + (l&15)]
// packed at element offset ((s*NT + t)*64 + l)*8 + j.
// ---------------------------------------------------------------------------
__global__ __launch_bounds__(256) void pack_all(
        const float* __restrict__ W0, const float* __restrict__ W1,
        const float* __restrict__ W2, const float* __restrict__ W3,
        const float* __restrict__ W4, const float* __restrict__ W5,
        ushort_t* H0, ushort_t* L0, ushort_t* H1, ushort_t* L1,
        ushort_t* H2, ushort_t* L2, ushort_t* H3, ushort_t* L3,
        ushort_t* H4, ushort_t* L4, ushort_t* H5, ushort_t* L5) {
    int b = blockIdx.x;
    const float* W; ushort_t* Hi; ushort_t* Lo; int K, NS, base;
    if (b < 8)       { W = W0; Hi = H0; Lo = L0; K = 128; NS = 128; base = 0;  }
    else if (b < 16) { W = W1; Hi = H1; Lo = L1; K = 128; NS = 128; base = 8;  }
    else if (b < 20) { W = W2; Hi = H2; Lo = L2; K = 128; NS = 64;  base = 16; }
    else if (b < 24) { W = W3; Hi = H3; Lo = L3; K = 128; NS = 64;  base = 20; }
    else if (b < 26) { W = W4; Hi = H4; Lo = L4; K = 64;  NS = 64;  base = 24; }
    else             { W = W5; Hi = H5; Lo = L5; K = 64;  NS = 64;  base = 26; }
    int tid = (b - base) * 256 + threadIdx.x;
    if (tid >= (K * NS) / 8) return;
    int l  = tid & 63;
    int fl = tid >> 6;
    int NT = NS / 16;
    int t = fl % NT, s = fl / NT;
    ushort_t hs[8], ls[8];
    #pragma unroll
    for (int j = 0; j < 8; ++j) {
        int k = s * 32 + (l >> 4) * 8 + j;
        int n = t * 16 + (l & 15);
        float w = W[(size_t)k * NS + n];
        ushort_t h = f2bf(w);
        hs[j] = h;
        ls[j] = f2bf(w - bf2f(h));
    }
    #pragma unroll
    for (int j = 0; j < 8; ++j) {
        Hi[(size_t)tid * 8 + j] = hs[j];
        Lo[(size_t)tid * 8 + j] = ls[j];
    }
}

// ---------------------------------------------------------------------------
// MFMA dual GEMM (split-bf16, fp32-grade):
//   S[M,NS]  = X @ Ws + bias  (fp32 out)
//   Zb[M,NS] = X @ Wn         (bf16 out)
// X fp32 row-major, split to hi/lo bf16 in-register. Weights pre-packed.
// Block: 256 thr = 4 waves; wave owns 32 rows (2 m-tiles); block = 128 rows.
// No LDS, no barriers. x ~= hi+lo; x*w ~= hi*hi + lo*hi + hi*lo.
// ---------------------------------------------------------------------------
template <int K, int NS>
__global__ __launch_bounds__(256) void mfma_gemm(const float* __restrict__ X,
                                                 const ushort_t* __restrict__ BsHi,
                                                 const ushort_t* __restrict__ BsLo,
                                                 const ushort_t* __restrict__ BnHi,
                                                 const ushort_t* __restrict__ BnLo,
                                                 const float* __restrict__ bias,
                                                 float* __restrict__ S,
                                                 ushort_t* __restrict__ Zb,
                                                 int M) {
    constexpr int KS = K / 32;      // mfma k-steps
    constexpr int NT = NS / 16;     // n-tiles
    int tid = threadIdx.x;
    int lane = tid & 63, w = tid >> 6;
    int baseM = blockIdx.x * 128 + w * 32;
    int rIn = lane & 15, q = lane >> 4;

    // ---- load + split all A fragments for this wave's 32 rows ----
    short8 Ahi[KS][2], Alo[KS][2];
    #pragma unroll
    for (int s = 0; s < KS; ++s) {
        #pragma unroll
        for (int mt = 0; mt < 2; ++mt) {
            int gm = baseM + mt * 16 + rIn;
            if (gm < M) {
                split8(&X[(size_t)gm * K + s * 32 + q * 8], Ahi[s][mt], Alo[s][mt]);
            } else {
                #pragma unroll
                for (int j = 0; j < 8; ++j) { Ahi[s][mt][j] = 0; Alo[s][mt][j] = 0; }
            }
        }
    }

    // ---- loop n-tiles; stream B frags from L2; 12 MFMA per (s,t) ----
    for (int t = 0; t < NT; ++t) {
        f32x4 aS0 = {0.f, 0.f, 0.f, 0.f}, aS1 = {0.f, 0.f, 0.f, 0.f};
        f32x4 aZ0 = {0.f, 0.f, 0.f, 0.f}, aZ1 = {0.f, 0.f, 0.f, 0.f};
        #pragma unroll
        for (int s = 0; s < KS; ++s) {
            size_t fo = ((size_t)(s * NT + t) * 64 + lane) * 8;
            short8 bsh = *(const short8*)&BsHi[fo];
            short8 bsl = *(const short8*)&BsLo[fo];
            short8 bnh = *(const short8*)&BnHi[fo];
            short8 bnl = *(const short8*)&BnLo[fo];
            aS0 = __builtin_amdgcn_mfma_f32_16x16x32_bf16(Ahi[s][0], bsh, aS0, 0, 0, 0);
            aS0 = __builtin_amdgcn_mfma_f32_16x16x32_bf16(Alo[s][0], bsh, aS0, 0, 0, 0);
            aS0 = __builtin_amdgcn_mfma_f32_16x16x32_bf16(Ahi[s][0], bsl, aS0, 0, 0, 0);
            aS1 = __builtin_amdgcn_mfma_f32_16x16x32_bf16(Ahi[s][1], bsh, aS1, 0, 0, 0);
            aS1 = __builtin_amdgcn_mfma_f32_16x16x32_bf16(Alo[s][1], bsh, aS1, 0, 0, 0);
            aS1 = __builtin_amdgcn_mfma_f32_16x16x32_bf16(Ahi[s][1], bsl, aS1, 0, 0, 0);
            aZ0 = __builtin_amdgcn_mfma_f32_16x16x32_bf16(Ahi[s][0], bnh, aZ0, 0, 0, 0);
            aZ0 = __builtin_amdgcn_mfma_f32_16x16x32_bf16(Alo[s][0], bnh, aZ0, 0, 0, 0);
            aZ0 = __builtin_amdgcn_mfma_f32_16x16x32_bf16(Ahi[s][0], bnl, aZ0, 0, 0, 0);
            aZ1 = __builtin_amdgcn_mfma_f32_16x16x32_bf16(Ahi[s][1], bnh, aZ1, 0, 0, 0);
            aZ1 = __builtin_amdgcn_mfma_f32_16x16x32_bf16(Alo[s][1], bnh, aZ1, 0, 0, 0);
            aZ1 = __builtin_amdgcn_mfma_f32_16x16x32_bf16(Ahi[s][1], bnl, aZ1, 0, 0, 0);
        }
        // epilogue: C/D layout col = lane&15, row = (lane>>4)*4 + reg
        int col = t * 16 + rIn;
        float bv = bias[col];
        #pragma unroll
        for (int mt = 0; mt < 2; ++mt) {
            f32x4 aS = mt ? aS1 : aS0;
            f32x4 aZ = mt ? aZ1 : aZ0;
            #pragma unroll
            for (int r = 0; r < 4; ++r) {
                int gm = baseM + mt * 16 + q * 4 + r;
                if (gm < M) {
                    S[(size_t)gm * NS + col]  = aS[r] + bv;
                    Zb[(size_t)gm * NS + col] = f2bf(aZ[r]);
                }
            }
        }
    }
}

// ---------------------------------------------------------------------------
// Aggregate with bf16 Z: out[n,f] = act( S[n,f] + inv_deg[n]*sum Z[src,f] )
// Each lane covers 4 features (uint2 = 4 bf16). ACT: 0 = relu, 1 = softmax(D=64)
// ---------------------------------------------------------------------------
template <int D, int ACT>
__global__ __launch_bounds__(256) void agg_kernel(const float* __restrict__ S,
                                                  const uint2* __restrict__ Zu,
                                                  const int* __restrict__ row_ptr,
                                                  const int* __restrict__ edge_src,
                                                  const float* __restrict__ inv_deg,
                                                  float* __restrict__ out, int N) {
    constexpr int G  = D / 4;          // lanes per node
    constexpr int NG = 256 / G;        // nodes per block
    int tid = threadIdx.x;
    int g = tid / G, f4 = tid % G;
    int n = blockIdx.x * NG + g;
    if (n >= N) return;
    int beg = row_ptr[n], end = row_ptr[n + 1];

    float a0[4] = {0, 0, 0, 0}, a1[4] = {0, 0, 0, 0};
    float a2[4] = {0, 0, 0, 0}, a3[4] = {0, 0, 0, 0};
#define ACC(u, a)                                                              \
    a[0] += __uint_as_float((u).x << 16);                                      \
    a[1] += __uint_as_float((u).x & 0xFFFF0000u);                              \
    a[2] += __uint_as_float((u).y << 16);                                      \
    a[3] += __uint_as_float((u).y & 0xFFFF0000u);
    int j = beg;
    for (; j + 3 < end; j += 4) {
        int s0 = edge_src[j + 0], s1 = edge_src[j + 1];
        int s2 = edge_src[j + 2], s3 = edge_src[j + 3];
        uint2 u0 = Zu[(size_t)s0 * G + f4];
        uint2 u1 = Zu[(size_t)s1 * G + f4];
        uint2 u2 = Zu[(size_t)s2 * G + f4];
        uint2 u3 = Zu[(size_t)s3 * G + f4];
        ACC(u0, a0) ACC(u1, a1) ACC(u2, a2) ACC(u3, a3)
    }
    for (; j < end; ++j) {
        uint2 u = Zu[(size_t)edge_src[j] * G + f4];
        ACC(u, a0)
    }
#undef ACC
    float id = inv_deg[n];
    float4 sv = ((const float4*)(S + (size_t)n * D))[f4];
    float v[4];
    v[0] = sv.x + id * ((a0[0] + a1[0]) + (a2[0] + a3[0]));
    v[1] = sv.y + id * ((a0[1] + a1[1]) + (a2[1] + a3[1]));
    v[2] = sv.z + id * ((a0[2] + a1[2]) + (a2[2] + a3[2]));
    v[3] = sv.w + id * ((a0[3] + a1[3]) + (a2[3] + a3[3]));

    float4 o;
    if (ACT == 0) {
        o.x = fmaxf(v[0], 0.f); o.y = fmaxf(v[1], 0.f);
        o.z = fmaxf(v[2], 0.f); o.w = fmaxf(v[3], 0.f);
    } else {
        // softmax across G=16 lanes x 4 vals
        float m = fmaxf(fmaxf(v[0], v[1]), fmaxf(v[2], v[3]));
        #pragma unroll
        for (int off = 8; off > 0; off >>= 1) m = fmaxf(m, __shfl_xor(m, off, 16));
        float e0 = __expf(v[0] - m), e1 = __expf(v[1] - m);
        float e2 = __expf(v[2] - m), e3 = __expf(v[3] - m);
        float s = (e0 + e1) + (e2 + e3);
        #pragma unroll
        for (int off = 8; off > 0; off >>= 1) s += __shfl_xor(s, off, 16);
        float inv = 1.0f / s;
        o.x = e0 * inv; o.y = e1 * inv; o.z = e2 * inv; o.w = e3 * inv;
    }
    ((float4*)(out + (size_t)n * D))[f4] = o;
}

// ---------------------------------------------------------------------------
extern "C" void kernel_launch(void* const* d_in, const int* in_sizes, int n_in,
                              void* d_out, int out_size, void* d_ws, size_t ws_size,
                              hipStream_t stream) {
    const float* in_feat = (const float*)d_in[0];
    const int*   src     = (const int*)d_in[1];
    const int*   dst     = (const int*)d_in[2];
    const float* w1s = (const float*)d_in[3];
    const float* w1n = (const float*)d_in[4];
    const float* b1  = (const float*)d_in[5];
    const float* w2s = (const float*)d_in[6];
    const float* w2n = (const float*)d_in[7];
    const float* b2  = (const float*)d_in[8];
    const float* w3s = (const float*)d_in[9];
    const float* w3n = (const float*)d_in[10];
    const float* b3  = (const float*)d_in[11];

    const int N = N_NODES;
    const int E = in_sizes[1];

    char* p = (char*)d_ws;
    auto carve = [&](size_t bytes) -> char* {
        char* q = p;
        p += (bytes + 511) & ~(size_t)511;
        return q;
    };
    float*    S        = (float*)   carve((size_t)N * 128 * sizeof(float));
    ushort_t* Zb       = (ushort_t*)carve((size_t)N * 128 * sizeof(ushort_t));
    float*    H        = (float*)   carve((size_t)N * 128 * sizeof(float));
    int*      edge_src = (int*)     carve((size_t)E * sizeof(int));
    int*      row_ptr  = (int*)     carve((size_t)(N + 1) * sizeof(int));
    int*      cursor   = (int*)     carve((size_t)N * sizeof(int));
    int*      deg      = (int*)     carve((size_t)N * sizeof(int));
    float*    invd     = (float*)   carve((size_t)N * sizeof(float));
    int*      partials = (int*)     carve(256 * sizeof(int));
    int*      gcur     = (int*)     carve(MAXBUCK * sizeof(int));
    // staging pairs alias H (H is only written after scatter completes)
    long long* staged  = (long long*)H;
    // packed weights (hi/lo per matrix)
    ushort_t* P1sH = (ushort_t*)carve(128 * 128 * 2); ushort_t* P1sL = (ushort_t*)carve(128 * 128 * 2);
    ushort_t* P1nH = (ushort_t*)carve(128 * 128 * 2); ushort_t* P1nL = (ushort_t*)carve(128 * 128 * 2);
    ushort_t* P2sH = (ushort_t*)carve(128 * 64 * 2);  ushort_t* P2sL = (ushort_t*)carve(128 * 64 * 2);
    ushort_t* P2nH = (ushort_t*)carve(128 * 64 * 2);  ushort_t* P2nL = (ushort_t*)carve(128 * 64 * 2);
    ushort_t* P3sH = (ushort_t*)carve(64 * 64 * 2);   ushort_t* P3sL = (ushort_t*)carve(64 * 64 * 2);
    ushort_t* P3nH = (ushort_t*)carve(64 * 64 * 2);   ushort_t* P3nL = (ushort_t*)carve(64 * 64 * 2);

    // ---- weight packing (single launch, 28 blocks) ----
    pack_all<<<28, 256, 0, stream>>>(w1s, w1n, w2s, w2n, w3s, w3n,
                                     P1sH, P1sL, P1nH, P1nL,
                                     P2sH, P2sL, P2nH, P2nL,
                                     P3sH, P3sL, P3nH, P3nL);

    // ---- CSR build ----
    (void)hipMemsetAsync(deg, 0, (size_t)N * sizeof(int), stream);
    hist_kernel<<<(E + 255) / 256, 256, 0, stream>>>(dst, deg, E);
    const int NB = (N + 1023) / 1024;   // 98 segments
    scan_partial_sums<<<NB, 256, 0, stream>>>(deg, partials, N);
    scan_partials<<<1, 256, 0, stream>>>(partials, NB, row_ptr, N);
    scan_emit<<<NB, 256, 0, stream>>>(deg, partials, row_ptr, cursor, invd, gcur, N);
    const int NBUCK = (N + 255) >> 8;          // 391 buckets of 256 nodes
    const int BINB  = 256;
    const int CHUNK = (E + BINB - 1) / BINB;
    bin_pairs<<<BINB, 256, 0, stream>>>(src, dst, gcur, staged, E, NBUCK, CHUNK);
    scatter_bucket<<<NBUCK, 256, 0, stream>>>(staged, row_ptr, cursor, edge_src, N);

    const int GB = (N + 127) / 128;   // 782 row blocks

    // ---- Layer 1: 128 -> 128, relu ----
    mfma_gemm<128, 128><<<GB, 256, 0, stream>>>(in_feat, P1sH, P1sL, P1nH, P1nL, b1, S, Zb, N);
    agg_kernel<128, 0><<<(N + 7) / 8, 256, 0, stream>>>(S, (const uint2*)Zb,
                                                        row_ptr, edge_src, invd, H, N);

    // ---- Layer 2: 128 -> 64, relu ----
    mfma_gemm<128, 64><<<GB, 256, 0, stream>>>(H, P2sH, P2sL, P2nH, P2nL, b2, S, Zb, N);
    agg_kernel<64, 0><<<(N + 15) / 16, 256, 0, stream>>>(S, (const uint2*)Zb,
                                                         row_ptr, edge_src, invd, H, N);

    // ---- Layer 3: 64 -> 64, softmax ----
    mfma_gemm<64, 64><<<GB, 256, 0, stream>>>(H, P3sH, P3sL, P3nH, P3nL, b3, S, Zb, N);
    agg_kernel<64, 1><<<(N + 15) / 16, 256, 0, stream>>>(S, (const uint2*)Zb,
                                                         row_ptr, edge_src, invd,
                                                         (float*)d_out, N);
}

// Round 9
// 474.604 us; speedup vs baseline: 1.7475x; 1.0636x over previous
//
#include <hip/hip_runtime.h>
#include <hip/hip_bf16.h>

#define N_NODES 100000

typedef unsigned short ushort_t;
typedef __attribute__((ext_vector_type(8))) short short8;
typedef __attribute__((ext_vector_type(4))) float f32x4;

// ---------------------------------------------------------------------------
// helpers
// ---------------------------------------------------------------------------
static __device__ __forceinline__ ushort_t f2bf(float f) {
    unsigned u = __float_as_uint(f);
    unsigned r = u + 0x7FFFu + ((u >> 16) & 1u);   // round-to-nearest-even
    return (ushort_t)(r >> 16);
}
static __device__ __forceinline__ float bf2f(ushort_t h) {
    return __uint_as_float(((unsigned)h) << 16);
}

// split 8 contiguous fp32 into hi/lo bf16 fragments
static __device__ __forceinline__ void split8(const float* __restrict__ xp,
                                              short8& hi, short8& lo) {
    float4 x0 = *(const float4*)xp;
    float4 x1 = *(const float4*)(xp + 4);
    float xs[8] = {x0.x, x0.y, x0.z, x0.w, x1.x, x1.y, x1.z, x1.w};
    #pragma unroll
    for (int j = 0; j < 8; ++j) {
        ushort_t h = f2bf(xs[j]);
        hi[j] = (short)h;
        lo[j] = (short)f2bf(xs[j] - bf2f(h));
    }
}

// ---------------------------------------------------------------------------
// CSR build: histogram -> 3-phase scan -> bucket-binning -> exclusive scatter
// ---------------------------------------------------------------------------
__global__ __launch_bounds__(256) void hist_kernel(const int* __restrict__ dst,
                                                   int* __restrict__ deg, int E) {
    int e = blockIdx.x * 256 + threadIdx.x;
    if (e < E) atomicAdd(&deg[__builtin_nontemporal_load(&dst[e])], 1);
}

// phase 1: per-block (1024-elem segment) total
__global__ __launch_bounds__(256) void scan_partial_sums(const int* __restrict__ deg,
                                                         int* __restrict__ partials, int N) {
    __shared__ int wsums[4];
    int tid = threadIdx.x, lane = tid & 63, wv = tid >> 6;
    int i0 = blockIdx.x * 1024 + tid * 4;
    int s = 0;
    #pragma unroll
    for (int j = 0; j < 4; ++j) {
        int i = i0 + j;
        if (i < N) s += deg[i];
    }
    #pragma unroll
    for (int off = 32; off > 0; off >>= 1) s += __shfl_xor(s, off, 64);
    if (lane == 0) wsums[wv] = s;
    __syncthreads();
    if (tid == 0)
        partials[blockIdx.x] = wsums[0] + wsums[1] + wsums[2] + wsums[3];
}

// phase 2: single block scans NB (<=256) partials -> exclusive, writes row_ptr[N]
__global__ __launch_bounds__(256) void scan_partials(int* __restrict__ partials, int NB,
                                                     int* __restrict__ row_ptr, int N) {
    __shared__ int wsums[4];
    int tid = threadIdx.x, lane = tid & 63, wv = tid >> 6;
    int v = (tid < NB) ? partials[tid] : 0;
    int x = v;
    #pragma unroll
    for (int off = 1; off < 64; off <<= 1) {
        int y = __shfl_up(x, off, 64);
        if (lane >= off) x += y;
    }
    if (lane == 63) wsums[wv] = x;
    __syncthreads();
    int woff = 0;
    for (int w = 0; w < wv; ++w) woff += wsums[w];
    int incl = x + woff;
    if (tid < NB) partials[tid] = incl - v;          // exclusive
    if (tid == NB - 1) row_ptr[N] = incl;            // grand total
}

// phase 3: emit row_ptr/cursor/invd; also init per-bucket cursor gcur
__global__ __launch_bounds__(256) void scan_emit(const int* __restrict__ deg,
                                                 const int* __restrict__ partials,
                                                 int* __restrict__ row_ptr,
                                                 int* __restrict__ cursor,
                                                 float* __restrict__ inv_deg,
                                                 int* __restrict__ gcur, int N) {
    __shared__ int wsums[4];
    int tid = threadIdx.x, lane = tid & 63, wv = tid >> 6;
    int i0 = blockIdx.x * 1024 + tid * 4;
    int d[4];
    #pragma unroll
    for (int j = 0; j < 4; ++j) {
        int i = i0 + j;
        d[j] = (i < N) ? deg[i] : 0;
    }
    int s = d[0] + d[1] + d[2] + d[3];
    int x = s;
    #pragma unroll
    for (int off = 1; off < 64; off <<= 1) {
        int y = __shfl_up(x, off, 64);
        if (lane >= off) x += y;
    }
    if (lane == 63) wsums[wv] = x;
    __syncthreads();
    int woff = 0;
    for (int w = 0; w < wv; ++w) woff += wsums[w];
    int run = partials[blockIdx.x] + woff + x - s;   // exclusive prefix of elem i0
    #pragma unroll
    for (int j = 0; j < 4; ++j) {
        int i = i0 + j;
        if (i < N) {
            row_ptr[i] = run;
            cursor[i]  = run;
            inv_deg[i] = 1.0f / (float)(d[j] > 0 ? d[j] : 1);
            if ((i & 255) == 0) gcur[i >> 8] = run;   // bucket staging base
            run += d[j];
        }
    }
}

// Phase A: bin (src,dst) pairs into bucket-ordered staging (bucket = dst>>8).
#define MAXBUCK 512
__global__ __launch_bounds__(256) void bin_pairs(const int* __restrict__ src,
                                                 const int* __restrict__ dst,
                                                 int* __restrict__ gcur,
                                                 long long* __restrict__ staged,
                                                 int E, int NBUCK, int C) {
    __shared__ int cnt[MAXBUCK];
    int tid = threadIdx.x;
    int e0 = blockIdx.x * C;
    int e1 = min(e0 + C, E);
    for (int b = tid; b < NBUCK; b += 256) cnt[b] = 0;
    __syncthreads();
    for (int e = e0 + tid; e < e1; e += 256) {
        int d = __builtin_nontemporal_load(&dst[e]);
        atomicAdd(&cnt[d >> 8], 1);
    }
    __syncthreads();
    for (int b = tid; b < NBUCK; b += 256) {
        int c = cnt[b];
        cnt[b] = (c > 0) ? atomicAdd(&gcur[b], c) : 0;   // now LDS cursor = global pos
    }
    __syncthreads();
    for (int e = e0 + tid; e < e1; e += 256) {
        int d = __builtin_nontemporal_load(&dst[e]);
        int s = __builtin_nontemporal_load(&src[e]);
        int p = atomicAdd(&cnt[d >> 8], 1);
        staged[p] = ((long long)d << 32) | (unsigned)s;   // hi=dst, lo=src
    }
}

// Phase B: one block per bucket; scatter within a private ~16KB edge_src window
__global__ __launch_bounds__(256) void scatter_bucket(const long long* __restrict__ staged,
                                                      const int* __restrict__ row_ptr,
                                                      int* __restrict__ cursor,
                                                      int* __restrict__ edge_src,
                                                      int N) {
    int b = blockIdx.x;
    int lo = b << 8;
    int hiN = min((b + 1) << 8, N);
    int gstart = row_ptr[lo];
    int gend   = row_ptr[hiN];
    for (int p = gstart + threadIdx.x; p < gend; p += 256) {
        long long pr = __builtin_nontemporal_load(&staged[p]);
        int d = (int)(pr >> 32);
        int s = (int)(pr & 0xFFFFFFFFll);
        int pos = atomicAdd(&cursor[d], 1);
        edge_src[pos] = s;
    }
}

// ---------------------------------------------------------------------------
// Weight pre-pack (all 6 matrices in ONE launch)
// ---------------------------------------------------------------------------
__global__ __launch_bounds__(256) void pack_all(
        const float* __restrict__ W0, const float* __restrict__ W1,
        const float* __restrict__ W2, const float* __restrict__ W3,
        const float* __restrict__ W4, const float* __restrict__ W5,
        ushort_t* H0, ushort_t* L0, ushort_t* H1, ushort_t* L1,
        ushort_t* H2, ushort_t* L2, ushort_t* H3, ushort_t* L3,
        ushort_t* H4, ushort_t* L4, ushort_t* H5, ushort_t* L5) {
    int b = blockIdx.x;
    const float* W; ushort_t* Hi; ushort_t* Lo; int K, NS, base;
    if (b < 8)       { W = W0; Hi = H0; Lo = L0; K = 128; NS = 128; base = 0;  }
    else if (b < 16) { W = W1; Hi = H1; Lo = L1; K = 128; NS = 128; base = 8;  }
    else if (b < 20) { W = W2; Hi = H2; Lo = L2; K = 128; NS = 64;  base = 16; }
    else if (b < 24) { W = W3; Hi = H3; Lo = L3; K = 128; NS = 64;  base = 20; }
    else if (b < 26) { W = W4; Hi = H4; Lo = L4; K = 64;  NS = 64;  base = 24; }
    else             { W = W5; Hi = H5; Lo = L5; K = 64;  NS = 64;  base = 26; }
    int tid = (b - base) * 256 + threadIdx.x;
    if (tid >= (K * NS) / 8) return;
    int l  = tid & 63;
    int fl = tid >> 6;
    int NT = NS / 16;
    int t = fl % NT, s = fl / NT;
    ushort_t hs[8], ls[8];
    #pragma unroll
    for (int j = 0; j < 8; ++j) {
        int k = s * 32 + (l >> 4) * 8 + j;
        int n = t * 16 + (l & 15);
        float w = W[(size_t)k * NS + n];
        ushort_t h = f2bf(w);
        hs[j] = h;
        ls[j] = f2bf(w - bf2f(h));
    }
    #pragma unroll
    for (int j = 0; j < 8; ++j) {
        Hi[(size_t)tid * 8 + j] = hs[j];
        Lo[(size_t)tid * 8 + j] = ls[j];
    }
}

// ---------------------------------------------------------------------------
// MFMA dual GEMM (split-bf16, fp32-grade) with LDS-transposed vector epilogue:
//   S[M,NS]  = X @ Ws + bias  (fp32 out, float4 stores)
//   Zb[M,NS] = X @ Wn         (bf16 out, uint2 stores)
// Per-wave private LDS staging (stride 20 words -> max 2-way bank alias, free;
// no barriers needed). R8 lesson: scalar epilogue stores caused 1.6x HBM write
// amplification + vmcnt stalls (123 MB vs 77 ideal, all pipes <25% busy).
// ---------------------------------------------------------------------------
template <int K, int NS>
__global__ __launch_bounds__(256) void mfma_gemm(const float* __restrict__ X,
                                                 const ushort_t* __restrict__ BsHi,
                                                 const ushort_t* __restrict__ BsLo,
                                                 const ushort_t* __restrict__ BnHi,
                                                 const ushort_t* __restrict__ BnLo,
                                                 const float* __restrict__ bias,
                                                 float* __restrict__ S,
                                                 ushort_t* __restrict__ Zb,
                                                 int M) {
    constexpr int KS = K / 32;      // mfma k-steps
    constexpr int NT = NS / 16;     // n-tiles
    __shared__ float ldsS[4][32 * 20];   // per-wave private transpose buffers
    __shared__ float ldsZ[4][32 * 20];
    int tid = threadIdx.x;
    int lane = tid & 63, w = tid >> 6;
    int baseM = blockIdx.x * 128 + w * 32;
    int rIn = lane & 15, q = lane >> 4;
    float* bufS = ldsS[w];
    float* bufZ = ldsZ[w];

    // ---- load + split all A fragments for this wave's 32 rows ----
    short8 Ahi[KS][2], Alo[KS][2];
    #pragma unroll
    for (int s = 0; s < KS; ++s) {
        #pragma unroll
        for (int mt = 0; mt < 2; ++mt) {
            int gm = baseM + mt * 16 + rIn;
            if (gm < M) {
                split8(&X[(size_t)gm * K + s * 32 + q * 8], Ahi[s][mt], Alo[s][mt]);
            } else {
                #pragma unroll
                for (int j = 0; j < 8; ++j) { Ahi[s][mt][j] = 0; Alo[s][mt][j] = 0; }
            }
        }
    }

    // ---- loop n-tiles; stream B frags from L2; 12 MFMA per (s,t) ----
    for (int t = 0; t < NT; ++t) {
        f32x4 aS0 = {0.f, 0.f, 0.f, 0.f}, aS1 = {0.f, 0.f, 0.f, 0.f};
        f32x4 aZ0 = {0.f, 0.f, 0.f, 0.f}, aZ1 = {0.f, 0.f, 0.f, 0.f};
        #pragma unroll
        for (int s = 0; s < KS; ++s) {
            size_t fo = ((size_t)(s * NT + t) * 64 + lane) * 8;
            short8 bsh = *(const short8*)&BsHi[fo];
            short8 bsl = *(const short8*)&BsLo[fo];
            short8 bnh = *(const short8*)&BnHi[fo];
            short8 bnl = *(const short8*)&BnLo[fo];
            aS0 = __builtin_amdgcn_mfma_f32_16x16x32_bf16(Ahi[s][0], bsh, aS0, 0, 0, 0);
            aS0 = __builtin_amdgcn_mfma_f32_16x16x32_bf16(Alo[s][0], bsh, aS0, 0, 0, 0);
            aS0 = __builtin_amdgcn_mfma_f32_16x16x32_bf16(Ahi[s][0], bsl, aS0, 0, 0, 0);
            aS1 = __builtin_amdgcn_mfma_f32_16x16x32_bf16(Ahi[s][1], bsh, aS1, 0, 0, 0);
            aS1 = __builtin_amdgcn_mfma_f32_16x16x32_bf16(Alo[s][1], bsh, aS1, 0, 0, 0);
            aS1 = __builtin_amdgcn_mfma_f32_16x16x32_bf16(Ahi[s][1], bsl, aS1, 0, 0, 0);
            aZ0 = __builtin_amdgcn_mfma_f32_16x16x32_bf16(Ahi[s][0], bnh, aZ0, 0, 0, 0);
            aZ0 = __builtin_amdgcn_mfma_f32_16x16x32_bf16(Alo[s][0], bnh, aZ0, 0, 0, 0);
            aZ0 = __builtin_amdgcn_mfma_f32_16x16x32_bf16(Ahi[s][0], bnl, aZ0, 0, 0, 0);
            aZ1 = __builtin_amdgcn_mfma_f32_16x16x32_bf16(Ahi[s][1], bnh, aZ1, 0, 0, 0);
            aZ1 = __builtin_amdgcn_mfma_f32_16x16x32_bf16(Alo[s][1], bnh, aZ1, 0, 0, 0);
            aZ1 = __builtin_amdgcn_mfma_f32_16x16x32_bf16(Ahi[s][1], bnl, aZ1, 0, 0, 0);
        }
        // ---- epilogue: C layout (col=rIn, row=q*4+r) -> LDS -> float4 stores
        #pragma unroll
        for (int r = 0; r < 4; ++r) {
            bufS[(q * 4 + r) * 20 + rIn]        = aS0[r];
            bufS[(16 + q * 4 + r) * 20 + rIn]   = aS1[r];
            bufZ[(q * 4 + r) * 20 + rIn]        = aZ0[r];
            bufZ[(16 + q * 4 + r) * 20 + rIn]   = aZ1[r];
        }
        int row = lane >> 2;            // 0..15
        int cq  = lane & 3;
        int col = t * 16 + cq * 4;
        float4 bv = *(const float4*)&bias[col];
        #pragma unroll
        for (int half = 0; half < 2; ++half) {
            int gm = baseM + half * 16 + row;
            float4 v = *(float4*)&bufS[(half * 16 + row) * 20 + cq * 4];
            float4 z = *(float4*)&bufZ[(half * 16 + row) * 20 + cq * 4];
            if (gm < M) {
                float4 o;
                o.x = v.x + bv.x; o.y = v.y + bv.y;
                o.z = v.z + bv.z; o.w = v.w + bv.w;
                *(float4*)&S[(size_t)gm * NS + col] = o;
                uint2 o2;
                o2.x = (unsigned)f2bf(z.x) | ((unsigned)f2bf(z.y) << 16);
                o2.y = (unsigned)f2bf(z.z) | ((unsigned)f2bf(z.w) << 16);
                *(uint2*)&Zb[(size_t)gm * NS + col] = o2;
            }
        }
    }
}

// ---------------------------------------------------------------------------
// Aggregate with bf16 Z: out[n,f] = act( S[n,f] + inv_deg[n]*sum Z[src,f] )
// Each lane covers 4 features (uint2 = 4 bf16). ACT: 0 = relu, 1 = softmax(D=64)
// ---------------------------------------------------------------------------
template <int D, int ACT>
__global__ __launch_bounds__(256) void agg_kernel(const float* __restrict__ S,
                                                  const uint2* __restrict__ Zu,
                                                  const int* __restrict__ row_ptr,
                                                  const int* __restrict__ edge_src,
                                                  const float* __restrict__ inv_deg,
                                                  float* __restrict__ out, int N) {
    constexpr int G  = D / 4;          // lanes per node
    constexpr int NG = 256 / G;        // nodes per block
    int tid = threadIdx.x;
    int g = tid / G, f4 = tid % G;
    int n = blockIdx.x * NG + g;
    if (n >= N) return;
    int beg = row_ptr[n], end = row_ptr[n + 1];

    float a0[4] = {0, 0, 0, 0}, a1[4] = {0, 0, 0, 0};
    float a2[4] = {0, 0, 0, 0}, a3[4] = {0, 0, 0, 0};
#define ACC(u, a)                                                              \
    a[0] += __uint_as_float((u).x << 16);                                      \
    a[1] += __uint_as_float((u).x & 0xFFFF0000u);                              \
    a[2] += __uint_as_float((u).y << 16);                                      \
    a[3] += __uint_as_float((u).y & 0xFFFF0000u);
    int j = beg;
    for (; j + 3 < end; j += 4) {
        int s0 = edge_src[j + 0], s1 = edge_src[j + 1];
        int s2 = edge_src[j + 2], s3 = edge_src[j + 3];
        uint2 u0 = Zu[(size_t)s0 * G + f4];
        uint2 u1 = Zu[(size_t)s1 * G + f4];
        uint2 u2 = Zu[(size_t)s2 * G + f4];
        uint2 u3 = Zu[(size_t)s3 * G + f4];
        ACC(u0, a0) ACC(u1, a1) ACC(u2, a2) ACC(u3, a3)
    }
    for (; j < end; ++j) {
        uint2 u = Zu[(size_t)edge_src[j] * G + f4];
        ACC(u, a0)
    }
#undef ACC
    float id = inv_deg[n];
    float4 sv = ((const float4*)(S + (size_t)n * D))[f4];
    float v[4];
    v[0] = sv.x + id * ((a0[0] + a1[0]) + (a2[0] + a3[0]));
    v[1] = sv.y + id * ((a0[1] + a1[1]) + (a2[1] + a3[1]));
    v[2] = sv.z + id * ((a0[2] + a1[2]) + (a2[2] + a3[2]));
    v[3] = sv.w + id * ((a0[3] + a1[3]) + (a2[3] + a3[3]));

    float4 o;
    if (ACT == 0) {
        o.x = fmaxf(v[0], 0.f); o.y = fmaxf(v[1], 0.f);
        o.z = fmaxf(v[2], 0.f); o.w = fmaxf(v[3], 0.f);
    } else {
        // softmax across G=16 lanes x 4 vals
        float m = fmaxf(fmaxf(v[0], v[1]), fmaxf(v[2], v[3]));
        #pragma unroll
        for (int off = 8; off > 0; off >>= 1) m = fmaxf(m, __shfl_xor(m, off, 16));
        float e0 = __expf(v[0] - m), e1 = __expf(v[1] - m);
        float e2 = __expf(v[2] - m), e3 = __expf(v[3] - m);
        float s = (e0 + e1) + (e2 + e3);
        #pragma unroll
        for (int off = 8; off > 0; off >>= 1) s += __shfl_xor(s, off, 16);
        float inv = 1.0f / s;
        o.x = e0 * inv; o.y = e1 * inv; o.z = e2 * inv; o.w = e3 * inv;
    }
    ((float4*)(out + (size_t)n * D))[f4] = o;
}

// ---------------------------------------------------------------------------
extern "C" void kernel_launch(void* const* d_in, const int* in_sizes, int n_in,
                              void* d_out, int out_size, void* d_ws, size_t ws_size,
                              hipStream_t stream) {
    const float* in_feat = (const float*)d_in[0];
    const int*   src     = (const int*)d_in[1];
    const int*   dst     = (const int*)d_in[2];
    const float* w1s = (const float*)d_in[3];
    const float* w1n = (const float*)d_in[4];
    const float* b1  = (const float*)d_in[5];
    const float* w2s = (const float*)d_in[6];
    const float* w2n = (const float*)d_in[7];
    const float* b2  = (const float*)d_in[8];
    const float* w3s = (const float*)d_in[9];
    const float* w3n = (const float*)d_in[10];
    const float* b3  = (const float*)d_in[11];

    const int N = N_NODES;
    const int E = in_sizes[1];

    char* p = (char*)d_ws;
    auto carve = [&](size_t bytes) -> char* {
        char* q = p;
        p += (bytes + 511) & ~(size_t)511;
        return q;
    };
    float*    S        = (float*)   carve((size_t)N * 128 * sizeof(float));
    ushort_t* Zb       = (ushort_t*)carve((size_t)N * 128 * sizeof(ushort_t));
    float*    H        = (float*)   carve((size_t)N * 128 * sizeof(float));
    int*      edge_src = (int*)     carve((size_t)E * sizeof(int));
    int*      row_ptr  = (int*)     carve((size_t)(N + 1) * sizeof(int));
    int*      cursor   = (int*)     carve((size_t)N * sizeof(int));
    int*      deg      = (int*)     carve((size_t)N * sizeof(int));
    float*    invd     = (float*)   carve((size_t)N * sizeof(float));
    int*      partials = (int*)     carve(256 * sizeof(int));
    int*      gcur     = (int*)     carve(MAXBUCK * sizeof(int));
    // staging pairs alias H (H is only written after scatter completes)
    long long* staged  = (long long*)H;
    // packed weights (hi/lo per matrix)
    ushort_t* P1sH = (ushort_t*)carve(128 * 128 * 2); ushort_t* P1sL = (ushort_t*)carve(128 * 128 * 2);
    ushort_t* P1nH = (ushort_t*)carve(128 * 128 * 2); ushort_t* P1nL = (ushort_t*)carve(128 * 128 * 2);
    ushort_t* P2sH = (ushort_t*)carve(128 * 64 * 2);  ushort_t* P2sL = (ushort_t*)carve(128 * 64 * 2);
    ushort_t* P2nH = (ushort_t*)carve(128 * 64 * 2);  ushort_t* P2nL = (ushort_t*)carve(128 * 64 * 2);
    ushort_t* P3sH = (ushort_t*)carve(64 * 64 * 2);   ushort_t* P3sL = (ushort_t*)carve(64 * 64 * 2);
    ushort_t* P3nH = (ushort_t*)carve(64 * 64 * 2);   ushort_t* P3nL = (ushort_t*)carve(64 * 64 * 2);

    // ---- weight packing (single launch, 28 blocks) ----
    pack_all<<<28, 256, 0, stream>>>(w1s, w1n, w2s, w2n, w3s, w3n,
                                     P1sH, P1sL, P1nH, P1nL,
                                     P2sH, P2sL, P2nH, P2nL,
                                     P3sH, P3sL, P3nH, P3nL);

    // ---- CSR build ----
    (void)hipMemsetAsync(deg, 0, (size_t)N * sizeof(int), stream);
    hist_kernel<<<(E + 255) / 256, 256, 0, stream>>>(dst, deg, E);
    const int NB = (N + 1023) / 1024;   // 98 segments
    scan_partial_sums<<<NB, 256, 0, stream>>>(deg, partials, N);
    scan_partials<<<1, 256, 0, stream>>>(partials, NB, row_ptr, N);
    scan_emit<<<NB, 256, 0, stream>>>(deg, partials, row_ptr, cursor, invd, gcur, N);
    const int NBUCK = (N + 255) >> 8;          // 391 buckets of 256 nodes
    const int BINB  = 256;
    const int CHUNK = (E + BINB - 1) / BINB;
    bin_pairs<<<BINB, 256, 0, stream>>>(src, dst, gcur, staged, E, NBUCK, CHUNK);
    scatter_bucket<<<NBUCK, 256, 0, stream>>>(staged, row_ptr, cursor, edge_src, N);

    const int GB = (N + 127) / 128;   // 782 row blocks

    // ---- Layer 1: 128 -> 128, relu ----
    mfma_gemm<128, 128><<<GB, 256, 0, stream>>>(in_feat, P1sH, P1sL, P1nH, P1nL, b1, S, Zb, N);
    agg_kernel<128, 0><<<(N + 7) / 8, 256, 0, stream>>>(S, (const uint2*)Zb,
                                                        row_ptr, edge_src, invd, H, N);

    // ---- Layer 2: 128 -> 64, relu ----
    mfma_gemm<128, 64><<<GB, 256, 0, stream>>>(H, P2sH, P2sL, P2nH, P2nL, b2, S, Zb, N);
    agg_kernel<64, 0><<<(N + 15) / 16, 256, 0, stream>>>(S, (const uint2*)Zb,
                                                         row_ptr, edge_src, invd, H, N);

    // ---- Layer 3: 64 -> 64, softmax ----
    mfma_gemm<64, 64><<<GB, 256, 0, stream>>>(H, P3sH, P3sL, P3nH, P3nL, b3, S, Zb, N);
    agg_kernel<64, 1><<<(N + 15) / 16, 256, 0, stream>>>(S, (const uint2*)Zb,
                                                         row_ptr, edge_src, invd,
                                                         (float*)d_out, N);
}